// Round 1
// baseline (3123.289 us; speedup 1.0000x reference)
//
#include <hip/hip_runtime.h>
#include <math.h>

#define BATCH 128
#define NNODE 1024
#define EG 16384
#define F_IN 64
#define HID 128
#define C1 64
#define C2 32
#define NCLS 4
#define POWER_ITERS 50
#define BN (BATCH * NNODE)

typedef float f32x4 __attribute__((ext_vector_type(4)));

// ---------------------------------------------------------------------------
// Kernel 1: lambda_max via power iteration + degree vector (single workgroup).
// Edges held in registers (16 per thread), v/u/deg in LDS.
// NOTE: edge_weight is uniform[0,1) so relu(w) == w; one deg array serves both
// the raw-weight lambda_max path and the relu'd forward path.
// ---------------------------------------------------------------------------
__global__ __launch_bounds__(1024) void k_lmax(
    const int* __restrict__ ei, const float* __restrict__ ew,
    float* __restrict__ scal, float* __restrict__ deg_g)
{
    __shared__ float v[NNODE];
    __shared__ float u[NNODE];
    __shared__ float dg[NNODE];
    __shared__ float red[17];
    const int t = threadIdx.x;

    int es[16], ed[16];
    float w[16];
#pragma unroll
    for (int i = 0; i < 16; ++i) {
        const int e = i * 1024 + t;       // coalesced
        es[i] = ei[e];
        ed[i] = ei[EG + e];
        w[i]  = ew[e];
    }

    dg[t] = 0.f;
    __syncthreads();
#pragma unroll
    for (int i = 0; i < 16; ++i) atomicAdd(&dg[es[i]], fmaxf(w[i], 0.f));
    __syncthreads();
    deg_g[t] = dg[t];

    v[t] = 0.03125f;   // 1/sqrt(1024)
    __syncthreads();

    for (int it = 0; it <= POWER_ITERS; ++it) {
        u[t] = dg[t] * v[t];
        __syncthreads();
#pragma unroll
        for (int i = 0; i < 16; ++i) atomicAdd(&u[ed[i]], -w[i] * v[es[i]]);
        __syncthreads();
        if (it == POWER_ITERS) break;     // final u = L@v for Rayleigh quotient

        float s = u[t] * u[t];
#pragma unroll
        for (int o = 32; o > 0; o >>= 1) s += __shfl_down(s, o, 64);
        if ((t & 63) == 0) red[t >> 6] = s;
        __syncthreads();
        if (t == 0) {
            float tot = 0.f;
            for (int i = 0; i < 16; ++i) tot += red[i];
            red[16] = sqrtf(tot) + 1e-12f;
        }
        __syncthreads();
        v[t] = u[t] / red[16];
        __syncthreads();
    }

    float s = v[t] * u[t];
#pragma unroll
    for (int o = 32; o > 0; o >>= 1) s += __shfl_down(s, o, 64);
    if ((t & 63) == 0) red[t >> 6] = s;
    __syncthreads();
    if (t == 0) {
        float lm = 0.f;
        for (int i = 0; i < 16; ++i) lm += red[i];
        scal[0] = lm;
        scal[1] = 2.0f / lm;
    }
}

// ---------------------------------------------------------------------------
// Kernel 2: out = A * lhat_mv(in) + Bc * base,  lhat_mv(X)=scale*(deg*X-agg)-X
// One workgroup per (graph, 32-feature chunk). agg[1024][32] in LDS (128KB).
// 256 threads = 8 edge-slots x 32 feature lanes; coalesced 128B x-row gathers.
// ---------------------------------------------------------------------------
__global__ __launch_bounds__(256) void k_prop(
    const float* __restrict__ in, const float* __restrict__ base,
    const int* __restrict__ ei, const float* __restrict__ ew,
    const float* __restrict__ deg_g, const float* __restrict__ scal,
    float* __restrict__ outp, float A, float Bc)
{
    __shared__ float agg[NNODE * 32];
    const int t  = threadIdx.x;
    const int b  = blockIdx.x >> 1;
    const int fc = blockIdx.x & 1;

    for (int i = t; i < NNODE * 32; i += 256) agg[i] = 0.f;
    __syncthreads();

    const int sub = t >> 5;   // 0..7 edge slot
    const int f   = t & 31;   // feature lane
    const float* xg = in + (size_t)b * (NNODE * F_IN) + fc * 32 + f;

#pragma unroll 2
    for (int e0 = 0; e0 < EG; e0 += 8) {
        const int e = e0 + sub;
        const int s = ei[e];
        const int d = ei[EG + e];
        const float ww = fmaxf(ew[e], 0.f);
        const float val = xg[(size_t)s * F_IN];
        atomicAdd(&agg[d * 32 + f], ww * val);
    }
    __syncthreads();

    const float scale = scal[1];
    for (int i = t; i < NNODE * 32; i += 256) {
        const int n = i >> 5, ff = i & 31;
        const size_t gi = (size_t)(b * NNODE + n) * F_IN + fc * 32 + ff;
        const float xv = in[gi];
        float r = scale * (deg_g[n] * xv - agg[i]) - xv;
        float o = A * r;
        if (Bc != 0.0f) o += Bc * base[gi];
        outp[gi] = o;
    }
}

// ---------------------------------------------------------------------------
// Kernel 3: fused Chebyshev GEMM (h = [tx0|tx1|tx2] @ Wcat + b) + conv1d+relu.
// 64-row tile per wg. Phase A: 8x4 micro-tile fp32 GEMM from LDS.
// Phase B: conv1d (128->64) + relu, write c[b][c1][n].
// LDS: Warea 96KB (chebW, later conv1d_W^T pad-68), Tarea 48KB (T, later h pad-132).
// ---------------------------------------------------------------------------
__global__ __launch_bounds__(256) void k_cheb_conv(
    const float* __restrict__ tx0, const float* __restrict__ tx1,
    const float* __restrict__ tx2,
    const float* __restrict__ chebW, const float* __restrict__ chebB,
    const float* __restrict__ convW, const float* __restrict__ convB,
    float* __restrict__ cout)
{
    __shared__ float Warea[24576];   // 96KB
    __shared__ float Tarea[12288];   // 48KB
    __shared__ float cb_s[HID];
    __shared__ float cvb_s[C1];

    const int t  = threadIdx.x;
    const int r0 = blockIdx.x * 64;   // global row (node) base
    const int bb = r0 >> 10;          // graph
    const int n0 = r0 & 1023;         // node base within graph

    // stage cheb_W (flat [3][64][128] == concat layout) via float4
    for (int i = t; i < 24576 / 4; i += 256)
        ((f32x4*)Warea)[i] = ((const f32x4*)chebW)[i];
    if (t < HID) cb_s[t] = chebB[t];
    if (t < C1)  cvb_s[t] = convB[t];

    // stage T tile: Ts[r][k], k<64: tx0, 64..127: tx1, 128..191: tx2
    {
        const float* srcs[3] = {tx0, tx1, tx2};
#pragma unroll
        for (int sIdx = 0; sIdx < 3; ++sIdx) {
            const float* sp = srcs[sIdx] + (size_t)r0 * F_IN;
            for (int i = t; i < 64 * 16; i += 256) {
                const int r = i >> 4, f4 = i & 15;
                ((f32x4*)Tarea)[r * 48 + sIdx * 16 + f4] =
                    ((const f32x4*)sp)[r * 16 + f4];
            }
        }
    }
    __syncthreads();

    // Phase A: 64x128 output, 8 rows x 4 cols per thread
    const int cg = t & 31;   // col group (4 cols)
    const int rg = t >> 5;   // row group (8 rows)
    f32x4 acc[8];
#pragma unroll
    for (int i = 0; i < 8; ++i) acc[i] = (f32x4)(0.f);

    for (int k0 = 0; k0 < 192; k0 += 4) {
        f32x4 av[8];
#pragma unroll
        for (int i = 0; i < 8; ++i)
            av[i] = *(const f32x4*)&Tarea[(rg * 8 + i) * 192 + k0];
#pragma unroll
        for (int j = 0; j < 4; ++j) {
            const f32x4 wv = *(const f32x4*)&Warea[(k0 + j) * 128 + cg * 4];
#pragma unroll
            for (int i = 0; i < 8; ++i) acc[i] += av[i][j] * wv;
        }
    }
    __syncthreads();   // done reading Warea/Tarea

    // write h (+bias) into Tarea as hs[64][132] (pad for banks)
    {
        const f32x4 cb4 = *(const f32x4*)&cb_s[cg * 4];
#pragma unroll
        for (int i = 0; i < 8; ++i)
            *(f32x4*)&Tarea[(rg * 8 + i) * 132 + cg * 4] = acc[i] + cb4;
    }
    // stage conv1d_W transposed into Warea: cwT[k*68 + c1]
    for (int i = t; i < C1 * HID; i += 256) {
        const int c1i = i >> 7, k = i & 127;
        Warea[k * 68 + c1i] = convW[i];
    }
    __syncthreads();

    // Phase B: 64 nodes x 64 channels, 4 c1 (vector) x 4 n per thread
    const int cg2 = t & 15;   // c1 group (4 channels)
    const int ng  = t >> 4;   // node group (4 nodes)
    f32x4 a2[4];
#pragma unroll
    for (int j = 0; j < 4; ++j) a2[j] = (f32x4)(0.f);

    for (int k = 0; k < HID; ++k) {
        const f32x4 wv = *(const f32x4*)&Warea[k * 68 + cg2 * 4];
#pragma unroll
        for (int j = 0; j < 4; ++j)
            a2[j] += Tarea[(ng * 4 + j) * 132 + k] * wv;
    }
#pragma unroll
    for (int j = 0; j < 4; ++j) {
        const int n = n0 + ng * 4 + j;
#pragma unroll
        for (int i = 0; i < 4; ++i) {
            const float val = a2[j][i] + cvb_s[cg2 * 4 + i];
            cout[(size_t)bb * (C1 * NNODE) + (size_t)(cg2 * 4 + i) * NNODE + n] =
                fmaxf(val, 0.f);
        }
    }
}

// ---------------------------------------------------------------------------
// Kernel 4: fc1 partials. z[b][j] = sum_i flat[b][i]*W1[j][i]. K-split: one wg
// per 256-column chunk; W chunk transposed (pad 33) in LDS; partials to ws.
// ---------------------------------------------------------------------------
__global__ __launch_bounds__(256) void k_fc1(
    const float* __restrict__ cf, const float* __restrict__ W,
    float* __restrict__ part)
{
    __shared__ float Wt[256 * 33];
    const int t = threadIdx.x;
    const int g = blockIdx.x;
    const int k0 = g * 256;

    for (int i = t; i < 8192; i += 256) {
        const int j = i >> 8, k = i & 255;
        Wt[k * 33 + j] = W[(size_t)j * (C1 * NNODE) + k0 + k];
    }
    __syncthreads();

    const int j = t & 31, bg = t >> 5;   // 8 b-groups x 16 b
    float acc[16];
#pragma unroll
    for (int i = 0; i < 16; ++i) acc[i] = 0.f;

    const float* cb = cf + (size_t)(bg * 16) * (C1 * NNODE) + k0;
    for (int k4 = 0; k4 < 64; ++k4) {
        const int kb = k4 * 4;
        const float w0 = Wt[(kb + 0) * 33 + j];
        const float w1 = Wt[(kb + 1) * 33 + j];
        const float w2 = Wt[(kb + 2) * 33 + j];
        const float w3 = Wt[(kb + 3) * 33 + j];
#pragma unroll
        for (int i = 0; i < 16; ++i) {
            const f32x4 cv = *(const f32x4*)&cb[(size_t)i * (C1 * NNODE) + kb];
            acc[i] += cv[0] * w0 + cv[1] * w1 + cv[2] * w2 + cv[3] * w3;
        }
    }
#pragma unroll
    for (int i = 0; i < 16; ++i)
        part[(size_t)g * 4096 + (size_t)(bg * 16 + i) * 32 + j] = acc[i];
}

// Kernel 4b: reduce the 256 partials (deterministic).
__global__ __launch_bounds__(256) void k_red(
    const float* __restrict__ part, float* __restrict__ z)
{
    const int o = blockIdx.x * 256 + threadIdx.x;
    float s = 0.f;
    for (int g = 0; g < 256; ++g) s += part[(size_t)g * 4096 + o];
    z[o] = s;
}

// Kernel 5: +fc1 bias, fc2, softmax. One thread per batch element.
__global__ __launch_bounds__(128) void k_head(
    const float* __restrict__ z, const float* __restrict__ b1,
    const float* __restrict__ W2, const float* __restrict__ b2,
    float* __restrict__ outp)
{
    const int b = threadIdx.x;
    float a[32];
#pragma unroll
    for (int j = 0; j < 32; ++j) a[j] = z[b * 32 + j] + b1[j];
    float l[4];
#pragma unroll
    for (int c = 0; c < 4; ++c) {
        float s = b2[c];
#pragma unroll
        for (int j = 0; j < 32; ++j) s += W2[c * 32 + j] * a[j];
        l[c] = s;
    }
    const float m = fmaxf(fmaxf(l[0], l[1]), fmaxf(l[2], l[3]));
    const float e0 = expf(l[0] - m), e1 = expf(l[1] - m);
    const float e2 = expf(l[2] - m), e3 = expf(l[3] - m);
    const float inv = 1.f / (e0 + e1 + e2 + e3);
    outp[b * 4 + 0] = e0 * inv;
    outp[b * 4 + 1] = e1 * inv;
    outp[b * 4 + 2] = e2 * inv;
    outp[b * 4 + 3] = e3 * inv;
}

// ---------------------------------------------------------------------------
extern "C" void kernel_launch(void* const* d_in, const int* in_sizes, int n_in,
                              void* d_out, int out_size, void* d_ws, size_t ws_size,
                              hipStream_t stream)
{
    const float* x     = (const float*)d_in[0];
    const int*   ei    = (const int*)d_in[1];
    const float* ew    = (const float*)d_in[2];
    const float* chebW = (const float*)d_in[3];
    const float* chebB = (const float*)d_in[4];
    const float* convW = (const float*)d_in[5];
    const float* convB = (const float*)d_in[6];
    const float* fc1W  = (const float*)d_in[7];
    const float* fc1B  = (const float*)d_in[8];
    const float* fc2W  = (const float*)d_in[9];
    const float* fc2B  = (const float*)d_in[10];
    float* out = (float*)d_out;

    char* ws = (char*)d_ws;
    const size_t SZ_TX = (size_t)BN * F_IN * 4;       // 33554432
    float* scal = (float*)(ws + 0);
    float* deg  = (float*)(ws + 256);
    float* tx1  = (float*)(ws + 8192);
    float* tx2  = (float*)(ws + 8192 + SZ_TX);
    float* cbuf = (float*)(ws + 8192 + 2 * SZ_TX);
    float* part = (float*)(ws + 8192 + 3 * SZ_TX);
    float* z    = (float*)(ws + 8192 + 3 * SZ_TX + 4194304);

    k_lmax<<<dim3(1), dim3(1024), 0, stream>>>(ei, ew, scal, deg);

    k_prop<<<dim3(256), dim3(256), 0, stream>>>(x, x, ei, ew, deg, scal,
                                                tx1, 1.f, 0.f);
    k_prop<<<dim3(256), dim3(256), 0, stream>>>(tx1, x, ei, ew, deg, scal,
                                                tx2, 2.f, -1.f);

    k_cheb_conv<<<dim3(BN / 64), dim3(256), 0, stream>>>(
        x, tx1, tx2, chebW, chebB, convW, convB, cbuf);

    k_fc1<<<dim3(256), dim3(256), 0, stream>>>(cbuf, fc1W, part);
    k_red<<<dim3(16), dim3(256), 0, stream>>>(part, z);
    k_head<<<dim3(1), dim3(128), 0, stream>>>(z, fc1B, fc2W, fc2B, out);
}

// Round 2
// 585.002 us; speedup vs baseline: 5.3389x; 5.3389x over previous
//
#include <hip/hip_runtime.h>
#include <math.h>

#define BATCH 128
#define NNODE 1024
#define EG 16384
#define F_IN 64
#define HID 128
#define C1 64
#define C2 32
#define NCLS 4
#define POWER_ITERS 50
#define BN (BATCH * NNODE)

typedef float f32x4 __attribute__((ext_vector_type(4)));

// ---------------------------------------------------------------------------
// CSR build (by dst): zero -> count -> scan -> fill. ~15us total.
// packed[p] = {float_as_int(raw_w), src}; deg_raw[s] = sum raw w (lmax),
// deg_relu[s] = sum relu(w) (forward). (Inputs are U[0,1) so equal, but cheap.)
// ---------------------------------------------------------------------------
__global__ __launch_bounds__(1024) void k_zero(int* cnt, float* dr, float* dl)
{
    const int t = threadIdx.x;
    cnt[t] = 0; dr[t] = 0.f; dl[t] = 0.f;
}

__global__ __launch_bounds__(256) void k_count(
    const int* __restrict__ ei, const float* __restrict__ ew,
    int* cnt, float* dr, float* dl)
{
    const int e = blockIdx.x * 256 + threadIdx.x;
    const int s = ei[e], d = ei[EG + e];
    const float w = ew[e];
    atomicAdd(&cnt[d], 1);
    atomicAdd(&dr[s], w);
    atomicAdd(&dl[s], fmaxf(w, 0.f));
}

__global__ __launch_bounds__(1024) void k_scan(
    const int* __restrict__ cnt, int* ptr, int* pos)
{
    __shared__ int s[1024];
    const int t = threadIdx.x;
    const int v = cnt[t];
    s[t] = v;
    __syncthreads();
    for (int o = 1; o < 1024; o <<= 1) {
        const int add = (t >= o) ? s[t - o] : 0;
        __syncthreads();
        s[t] += add;
        __syncthreads();
    }
    const int excl = s[t] - v;
    ptr[t] = excl; pos[t] = excl;
    if (t == 1023) ptr[1024] = s[1023];
}

__global__ __launch_bounds__(256) void k_fill(
    const int* __restrict__ ei, const float* __restrict__ ew,
    int* pos, int2* packed)
{
    const int e = blockIdx.x * 256 + threadIdx.x;
    const int s = ei[e], d = ei[EG + e];
    const float w = ew[e];
    const int p = atomicAdd(&pos[d], 1);
    packed[p] = make_int2(__float_as_int(w), s);
}

// ---------------------------------------------------------------------------
// Kernel 1: lambda_max power iteration, CSR fully LDS-resident, gather-based.
// Thread t owns node t. No atomics. 3 barriers/iter.
// ---------------------------------------------------------------------------
__global__ __launch_bounds__(1024) void k_lmax(
    const int2* __restrict__ packed, const int* __restrict__ ptr,
    const float* __restrict__ deg_raw, float* __restrict__ scal)
{
    __shared__ int2 eL[EG];        // 128KB
    __shared__ float v[NNODE];     // 4KB
    __shared__ float red[17];
    const int t = threadIdx.x;

    for (int i = t; i < EG; i += 1024) eL[i] = packed[i];
    const int p0 = ptr[t], p1 = ptr[t + 1];
    const float dgv = deg_raw[t];
    v[t] = 0.03125f;   // 1/sqrt(1024)
    __syncthreads();

    float u;
    for (int it = 0;; ++it) {
        u = dgv * v[t];
        for (int p = p0; p < p1; ++p) {
            const int2 e = eL[p];
            u -= __int_as_float(e.x) * v[e.y];
        }
        if (it == POWER_ITERS) break;   // final u = L@v for Rayleigh quotient

        float s = u * u;
#pragma unroll
        for (int o = 32; o > 0; o >>= 1) s += __shfl_down(s, o, 64);
        if ((t & 63) == 0) red[t >> 6] = s;
        __syncthreads();
        if (t == 0) {
            float tot = 0.f;
            for (int i = 0; i < 16; ++i) tot += red[i];
            red[16] = 1.0f / (sqrtf(tot) + 1e-12f);
        }
        __syncthreads();
        const float inv = red[16];
        v[t] = u * inv;
        __syncthreads();
    }

    float s = v[t] * u;
#pragma unroll
    for (int o = 32; o > 0; o >>= 1) s += __shfl_down(s, o, 64);
    if ((t & 63) == 0) red[t >> 6] = s;
    __syncthreads();
    if (t == 0) {
        float lm = 0.f;
        for (int i = 0; i < 16; ++i) lm += red[i];
        scal[0] = lm;
        scal[1] = 2.0f / lm;
    }
}

// ---------------------------------------------------------------------------
// Kernel 2: out = A * lhat_mv(in) + Bc * base, gather-based via dst-CSR.
// One wave per node (lane = feature, F_IN==64). No LDS, no atomics.
// XCD swizzle: 4096 consecutive node-blocks (16 graphs, 4MB of x) per XCD.
// ---------------------------------------------------------------------------
__global__ __launch_bounds__(256) void k_prop(
    const float* __restrict__ in, const float* __restrict__ base,
    const int2* __restrict__ packed, const int* __restrict__ ptr,
    const float* __restrict__ deg_relu, const float* __restrict__ scal,
    float* __restrict__ outp, float A, float Bc)
{
    const int bid   = ((blockIdx.x & 7) << 12) + (blockIdx.x >> 3);
    const int gnode = bid * 4 + (threadIdx.x >> 6);
    const int lane  = threadIdx.x & 63;
    const int b = gnode >> 10, d = gnode & 1023;

    const int p0 = ptr[d], p1 = ptr[d + 1];
    const float* xb = in + (size_t)b * (NNODE * F_IN);

    float acc = 0.f;
    int p = p0;
    for (; p + 2 <= p1; p += 2) {        // 2-deep MLP
        const int2 e0 = packed[p], e1 = packed[p + 1];
        const float v0 = xb[(size_t)e0.y * F_IN + lane];
        const float v1 = xb[(size_t)e1.y * F_IN + lane];
        acc += fmaxf(__int_as_float(e0.x), 0.f) * v0;
        acc += fmaxf(__int_as_float(e1.x), 0.f) * v1;
    }
    if (p < p1) {
        const int2 e = packed[p];
        acc += fmaxf(__int_as_float(e.x), 0.f) * xb[(size_t)e.y * F_IN + lane];
    }

    const float scale = scal[1];
    const size_t gi = (size_t)gnode * F_IN + lane;
    const float xv = in[gi];
    const float r = scale * (deg_relu[d] * xv - acc) - xv;
    float o = A * r;
    if (Bc != 0.0f) o += Bc * base[gi];
    outp[gi] = o;
}

// ---------------------------------------------------------------------------
// Kernel 3: fused Chebyshev GEMM (h = [tx0|tx1|tx2] @ Wcat + b) + conv1d+relu.
// 64-row tile per wg. Phase A: 8x4 micro-tile fp32 GEMM from LDS.
// Phase B: conv1d (128->64) + relu, write c[b][c1][n].
// ---------------------------------------------------------------------------
__global__ __launch_bounds__(256) void k_cheb_conv(
    const float* __restrict__ tx0, const float* __restrict__ tx1,
    const float* __restrict__ tx2,
    const float* __restrict__ chebW, const float* __restrict__ chebB,
    const float* __restrict__ convW, const float* __restrict__ convB,
    float* __restrict__ cout)
{
    __shared__ float Warea[24576];   // 96KB
    __shared__ float Tarea[12288];   // 48KB
    __shared__ float cb_s[HID];
    __shared__ float cvb_s[C1];

    const int t  = threadIdx.x;
    const int r0 = blockIdx.x * 64;
    const int bb = r0 >> 10;
    const int n0 = r0 & 1023;

    for (int i = t; i < 24576 / 4; i += 256)
        ((f32x4*)Warea)[i] = ((const f32x4*)chebW)[i];
    if (t < HID) cb_s[t] = chebB[t];
    if (t < C1)  cvb_s[t] = convB[t];

    {
        const float* srcs[3] = {tx0, tx1, tx2};
#pragma unroll
        for (int sIdx = 0; sIdx < 3; ++sIdx) {
            const float* sp = srcs[sIdx] + (size_t)r0 * F_IN;
            for (int i = t; i < 64 * 16; i += 256) {
                const int r = i >> 4, f4 = i & 15;
                ((f32x4*)Tarea)[r * 48 + sIdx * 16 + f4] =
                    ((const f32x4*)sp)[r * 16 + f4];
            }
        }
    }
    __syncthreads();

    const int cg = t & 31;
    const int rg = t >> 5;
    f32x4 acc[8];
#pragma unroll
    for (int i = 0; i < 8; ++i) acc[i] = (f32x4)(0.f);

    for (int k0 = 0; k0 < 192; k0 += 4) {
        f32x4 av[8];
#pragma unroll
        for (int i = 0; i < 8; ++i)
            av[i] = *(const f32x4*)&Tarea[(rg * 8 + i) * 192 + k0];
#pragma unroll
        for (int j = 0; j < 4; ++j) {
            const f32x4 wv = *(const f32x4*)&Warea[(k0 + j) * 128 + cg * 4];
#pragma unroll
            for (int i = 0; i < 8; ++i) acc[i] += av[i][j] * wv;
        }
    }
    __syncthreads();

    {
        const f32x4 cb4 = *(const f32x4*)&cb_s[cg * 4];
#pragma unroll
        for (int i = 0; i < 8; ++i)
            *(f32x4*)&Tarea[(rg * 8 + i) * 132 + cg * 4] = acc[i] + cb4;
    }
    for (int i = t; i < C1 * HID; i += 256) {
        const int c1i = i >> 7, k = i & 127;
        Warea[k * 68 + c1i] = convW[i];
    }
    __syncthreads();

    const int cg2 = t & 15;
    const int ng  = t >> 4;
    f32x4 a2[4];
#pragma unroll
    for (int j = 0; j < 4; ++j) a2[j] = (f32x4)(0.f);

    for (int k = 0; k < HID; ++k) {
        const f32x4 wv = *(const f32x4*)&Warea[k * 68 + cg2 * 4];
#pragma unroll
        for (int j = 0; j < 4; ++j)
            a2[j] += Tarea[(ng * 4 + j) * 132 + k] * wv;
    }
#pragma unroll
    for (int j = 0; j < 4; ++j) {
        const int n = n0 + ng * 4 + j;
#pragma unroll
        for (int i = 0; i < 4; ++i) {
            const float val = a2[j][i] + cvb_s[cg2 * 4 + i];
            cout[(size_t)bb * (C1 * NNODE) + (size_t)(cg2 * 4 + i) * NNODE + n] =
                fmaxf(val, 0.f);
        }
    }
}

// ---------------------------------------------------------------------------
// Kernel 4: fc1 partials (K-split over 256-col chunks), then reduce.
// ---------------------------------------------------------------------------
__global__ __launch_bounds__(256) void k_fc1(
    const float* __restrict__ cf, const float* __restrict__ W,
    float* __restrict__ part)
{
    __shared__ float Wt[256 * 33];
    const int t = threadIdx.x;
    const int g = blockIdx.x;
    const int k0 = g * 256;

    for (int i = t; i < 8192; i += 256) {
        const int j = i >> 8, k = i & 255;
        Wt[k * 33 + j] = W[(size_t)j * (C1 * NNODE) + k0 + k];
    }
    __syncthreads();

    const int j = t & 31, bg = t >> 5;
    float acc[16];
#pragma unroll
    for (int i = 0; i < 16; ++i) acc[i] = 0.f;

    const float* cb = cf + (size_t)(bg * 16) * (C1 * NNODE) + k0;
    for (int k4 = 0; k4 < 64; ++k4) {
        const int kb = k4 * 4;
        const float w0 = Wt[(kb + 0) * 33 + j];
        const float w1 = Wt[(kb + 1) * 33 + j];
        const float w2 = Wt[(kb + 2) * 33 + j];
        const float w3 = Wt[(kb + 3) * 33 + j];
#pragma unroll
        for (int i = 0; i < 16; ++i) {
            const f32x4 cv = *(const f32x4*)&cb[(size_t)i * (C1 * NNODE) + kb];
            acc[i] += cv[0] * w0 + cv[1] * w1 + cv[2] * w2 + cv[3] * w3;
        }
    }
#pragma unroll
    for (int i = 0; i < 16; ++i)
        part[(size_t)g * 4096 + (size_t)(bg * 16 + i) * 32 + j] = acc[i];
}

__global__ __launch_bounds__(256) void k_red(
    const float* __restrict__ part, float* __restrict__ z)
{
    const int o = blockIdx.x * 256 + threadIdx.x;
    float s = 0.f;
    for (int g = 0; g < 256; ++g) s += part[(size_t)g * 4096 + o];
    z[o] = s;
}

__global__ __launch_bounds__(128) void k_head(
    const float* __restrict__ z, const float* __restrict__ b1,
    const float* __restrict__ W2, const float* __restrict__ b2,
    float* __restrict__ outp)
{
    const int b = threadIdx.x;
    float a[32];
#pragma unroll
    for (int j = 0; j < 32; ++j) a[j] = z[b * 32 + j] + b1[j];
    float l[4];
#pragma unroll
    for (int c = 0; c < 4; ++c) {
        float s = b2[c];
#pragma unroll
        for (int j = 0; j < 32; ++j) s += W2[c * 32 + j] * a[j];
        l[c] = s;
    }
    const float m = fmaxf(fmaxf(l[0], l[1]), fmaxf(l[2], l[3]));
    const float e0 = expf(l[0] - m), e1 = expf(l[1] - m);
    const float e2 = expf(l[2] - m), e3 = expf(l[3] - m);
    const float inv = 1.f / (e0 + e1 + e2 + e3);
    outp[b * 4 + 0] = e0 * inv;
    outp[b * 4 + 1] = e1 * inv;
    outp[b * 4 + 2] = e2 * inv;
    outp[b * 4 + 3] = e3 * inv;
}

// ---------------------------------------------------------------------------
extern "C" void kernel_launch(void* const* d_in, const int* in_sizes, int n_in,
                              void* d_out, int out_size, void* d_ws, size_t ws_size,
                              hipStream_t stream)
{
    const float* x     = (const float*)d_in[0];
    const int*   ei    = (const int*)d_in[1];
    const float* ew    = (const float*)d_in[2];
    const float* chebW = (const float*)d_in[3];
    const float* chebB = (const float*)d_in[4];
    const float* convW = (const float*)d_in[5];
    const float* convB = (const float*)d_in[6];
    const float* fc1W  = (const float*)d_in[7];
    const float* fc1B  = (const float*)d_in[8];
    const float* fc2W  = (const float*)d_in[9];
    const float* fc2B  = (const float*)d_in[10];
    float* out = (float*)d_out;

    char* ws = (char*)d_ws;
    const size_t SZ_TX = (size_t)BN * F_IN * 4;       // 32MB
    float* scal = (float*)(ws + 0);
    float* tx1  = (float*)(ws + 8192);
    float* tx2  = (float*)(ws + 8192 + SZ_TX);
    float* cbuf = (float*)(ws + 8192 + 2 * SZ_TX);
    char*  partb = ws + 8192 + 3 * SZ_TX;             // 4MB region
    float* part = (float*)partb;
    float* z    = (float*)(ws + 8192 + 3 * SZ_TX + 4194304);

    // CSR scratch overlapped with `part` (dead before k_fc1 writes part).
    int*   cnt  = (int*)(partb + 0);
    int*   pos  = (int*)(partb + 4096);
    int*   ptr  = (int*)(partb + 8192);               // 1025 ints
    float* dgr  = (float*)(partb + 16384);            // raw deg (lmax)
    float* dgl  = (float*)(partb + 20480);            // relu deg (forward)
    int2*  pk   = (int2*)(partb + 24576);             // 128KB packed CSR

    // CSR build
    k_zero <<<dim3(1),  dim3(1024), 0, stream>>>(cnt, dgr, dgl);
    k_count<<<dim3(64), dim3(256),  0, stream>>>(ei, ew, cnt, dgr, dgl);
    k_scan <<<dim3(1),  dim3(1024), 0, stream>>>(cnt, ptr, pos);
    k_fill <<<dim3(64), dim3(256),  0, stream>>>(ei, ew, pos, pk);

    k_lmax<<<dim3(1), dim3(1024), 0, stream>>>(pk, ptr, dgr, scal);

    k_prop<<<dim3(BN / 4), dim3(256), 0, stream>>>(x, x, pk, ptr, dgl, scal,
                                                   tx1, 1.f, 0.f);
    k_prop<<<dim3(BN / 4), dim3(256), 0, stream>>>(tx1, x, pk, ptr, dgl, scal,
                                                   tx2, 2.f, -1.f);

    k_cheb_conv<<<dim3(BN / 64), dim3(256), 0, stream>>>(
        x, tx1, tx2, chebW, chebB, convW, convB, cbuf);

    k_fc1<<<dim3(256), dim3(256), 0, stream>>>(cbuf, fc1W, part);
    k_red<<<dim3(16), dim3(256), 0, stream>>>(part, z);
    k_head<<<dim3(1), dim3(128), 0, stream>>>(z, fc1B, fc2W, fc2B, out);
}

// Round 3
// 422.164 us; speedup vs baseline: 7.3983x; 1.3857x over previous
//
#include <hip/hip_runtime.h>
#include <math.h>

#define BATCH 128
#define NNODE 1024
#define EG 16384
#define F_IN 64
#define HID 128
#define C1 64
#define C2 32
#define NCLS 4
#define POWER_ITERS 50
#define BN (BATCH * NNODE)

typedef float f32x4 __attribute__((ext_vector_type(4)));
typedef __bf16 bf16x8 __attribute__((ext_vector_type(8)));

__device__ inline unsigned short f2bf(float f) {   // round-to-nearest-even
    unsigned int u = __float_as_uint(f);
    u += 0x7fffu + ((u >> 16) & 1u);
    return (unsigned short)(u >> 16);
}

// ---------------------------------------------------------------------------
// CSR build (by dst): zero -> count -> scan -> fill.
// ---------------------------------------------------------------------------
__global__ __launch_bounds__(1024) void k_zero(int* cnt, float* dr, float* dl)
{
    const int t = threadIdx.x;
    cnt[t] = 0; dr[t] = 0.f; dl[t] = 0.f;
}

__global__ __launch_bounds__(256) void k_count(
    const int* __restrict__ ei, const float* __restrict__ ew,
    int* cnt, float* dr, float* dl)
{
    const int e = blockIdx.x * 256 + threadIdx.x;
    const int s = ei[e], d = ei[EG + e];
    const float w = ew[e];
    atomicAdd(&cnt[d], 1);
    atomicAdd(&dr[s], w);
    atomicAdd(&dl[s], fmaxf(w, 0.f));
}

__global__ __launch_bounds__(1024) void k_scan(
    const int* __restrict__ cnt, int* ptr, int* pos)
{
    __shared__ int s[1024];
    const int t = threadIdx.x;
    const int v = cnt[t];
    s[t] = v;
    __syncthreads();
    for (int o = 1; o < 1024; o <<= 1) {
        const int add = (t >= o) ? s[t - o] : 0;
        __syncthreads();
        s[t] += add;
        __syncthreads();
    }
    const int excl = s[t] - v;
    ptr[t] = excl; pos[t] = excl;
    if (t == 1023) ptr[1024] = s[1023];
}

__global__ __launch_bounds__(256) void k_fill(
    const int* __restrict__ ei, const float* __restrict__ ew,
    int* pos, int2* packed)
{
    const int e = blockIdx.x * 256 + threadIdx.x;
    const int s = ei[e], d = ei[EG + e];
    const float w = ew[e];
    const int p = atomicAdd(&pos[d], 1);
    packed[p] = make_int2(__float_as_int(w), s);
}

// Convert/transpose weights to bf16: wcatT[n=128][k=192] from chebW[k][n];
// cvw[c1=64][k=128] straight copy of convW.
__global__ __launch_bounds__(256) void k_cvtw(
    const float* __restrict__ chebW, const float* __restrict__ convW,
    unsigned short* __restrict__ wcatT, unsigned short* __restrict__ cvw)
{
    const int i = blockIdx.x * 256 + threadIdx.x;
    if (i < 24576) {
        const int n = i / 192, k = i % 192;
        wcatT[i] = f2bf(chebW[k * 128 + n]);
    }
    const int j = i - 24576;
    if (j >= 0 && j < 8192) cvw[j] = f2bf(convW[j]);
}

// ---------------------------------------------------------------------------
// Kernel 1: lambda_max power iteration, CSR fully LDS-resident, gather-based.
// ---------------------------------------------------------------------------
__global__ __launch_bounds__(1024) void k_lmax(
    const int2* __restrict__ packed, const int* __restrict__ ptr,
    const float* __restrict__ deg_raw, float* __restrict__ scal)
{
    __shared__ int2 eL[EG];        // 128KB
    __shared__ float v[NNODE];
    __shared__ float red[17];
    const int t = threadIdx.x;

    for (int i = t; i < EG; i += 1024) eL[i] = packed[i];
    const int p0 = ptr[t], p1 = ptr[t + 1];
    const float dgv = deg_raw[t];
    v[t] = 0.03125f;   // 1/sqrt(1024)
    __syncthreads();

    float u;
    for (int it = 0;; ++it) {
        u = dgv * v[t];
        for (int p = p0; p < p1; ++p) {
            const int2 e = eL[p];
            u -= __int_as_float(e.x) * v[e.y];
        }
        if (it == POWER_ITERS) break;

        float s = u * u;
#pragma unroll
        for (int o = 32; o > 0; o >>= 1) s += __shfl_down(s, o, 64);
        if ((t & 63) == 0) red[t >> 6] = s;
        __syncthreads();
        if (t == 0) {
            float tot = 0.f;
            for (int i = 0; i < 16; ++i) tot += red[i];
            red[16] = 1.0f / (sqrtf(tot) + 1e-12f);
        }
        __syncthreads();
        const float inv = red[16];
        v[t] = u * inv;
        __syncthreads();
    }

    float s = v[t] * u;
#pragma unroll
    for (int o = 32; o > 0; o >>= 1) s += __shfl_down(s, o, 64);
    if ((t & 63) == 0) red[t >> 6] = s;
    __syncthreads();
    if (t == 0) {
        float lm = 0.f;
        for (int i = 0; i < 16; ++i) lm += red[i];
        scal[0] = lm;
        scal[1] = 2.0f / lm;
    }
}

// ---------------------------------------------------------------------------
// Kernel 2: out = A * lhat_mv(in) + Bc * base (gather, wave-per-node).
// Also emits bf16 slice into tcat[node][192] (x|tx1|tx2 concat along K).
// ---------------------------------------------------------------------------
__global__ __launch_bounds__(256) void k_prop(
    const float* __restrict__ in, const float* __restrict__ base,
    const int2* __restrict__ packed, const int* __restrict__ ptr,
    const float* __restrict__ deg_relu, const float* __restrict__ scal,
    float* __restrict__ out32, unsigned short* __restrict__ tcat,
    int slice, int writeX, float A, float Bc)
{
    const int bid   = ((blockIdx.x & 7) << 12) + (blockIdx.x >> 3);
    const int gnode = bid * 4 + (threadIdx.x >> 6);
    const int lane  = threadIdx.x & 63;
    const int b = gnode >> 10, d = gnode & 1023;

    const int p0 = ptr[d], p1 = ptr[d + 1];
    const float* xb = in + (size_t)b * (NNODE * F_IN);

    float acc = 0.f;
    int p = p0;
    for (; p + 2 <= p1; p += 2) {
        const int2 e0 = packed[p], e1 = packed[p + 1];
        const float v0 = xb[(size_t)e0.y * F_IN + lane];
        const float v1 = xb[(size_t)e1.y * F_IN + lane];
        acc += fmaxf(__int_as_float(e0.x), 0.f) * v0;
        acc += fmaxf(__int_as_float(e1.x), 0.f) * v1;
    }
    if (p < p1) {
        const int2 e = packed[p];
        acc += fmaxf(__int_as_float(e.x), 0.f) * xb[(size_t)e.y * F_IN + lane];
    }

    const float scale = scal[1];
    const size_t gi = (size_t)gnode * F_IN + lane;
    const float xv = in[gi];
    const float r = scale * (deg_relu[d] * xv - acc) - xv;
    float o = A * r;
    if (Bc != 0.0f) o += Bc * base[gi];
    if (out32) out32[gi] = o;
    tcat[(size_t)gnode * 192 + slice * 64 + lane] = f2bf(o);
    if (writeX) tcat[(size_t)gnode * 192 + lane] = f2bf(xv);
}

// ---------------------------------------------------------------------------
// Kernel 3: bf16 MFMA fused cheb-GEMM + conv1d.
// Phase A: h[128rows][128] = tcat[rows][192] @ Wcat[192][128]  (A from global,
//          W^T in LDS XOR-swizzled). Phase B: c = relu(convW @ h^T + b) via a
//          second MFMA pass (h restaged to LDS as bf16).
// ---------------------------------------------------------------------------
__global__ __launch_bounds__(256) void k_cheb_mfma(
    const unsigned short* __restrict__ tcat,
    const unsigned short* __restrict__ wcatT,
    const unsigned short* __restrict__ cvw,
    const float* __restrict__ chebB, const float* __restrict__ convB,
    float* __restrict__ cout)
{
    __shared__ __align__(16) char smem[49152];   // Bs (48K) / hS(32K)+cwS(16K)
    __shared__ float cb_s[HID];
    __shared__ float cvb_s[C1];

    const int t    = threadIdx.x;
    const int lane = t & 63;
    const int wid  = t >> 6;
    const int l15  = lane & 15;
    const int l4   = lane >> 4;
    const int rbase = blockIdx.x * 128;
    const int bb = rbase >> 10;
    const int n0 = rbase & 1023;

    if (t < HID) cb_s[t] = chebB[t];
    if (t < C1)  cvb_s[t] = convB[t];

    // stage W^T [n=128][k-slot 0..23] with slot XOR (n&7) swizzle
    for (int it = 0; it < 12; ++it) {
        const int gslot = it * 256 + t;          // 0..3071
        const int n = gslot / 24, q = gslot % 24;
        const bf16x8 v = *(const bf16x8*)(wcatT + n * 192 + q * 8);
        *(bf16x8*)(smem + n * 384 + ((q ^ (n & 7)) << 4)) = v;
    }
    __syncthreads();

    // ---- Phase A: 16x16x32 MFMA, A-frags straight from global ----
    const int rw = rbase + wid * 32;
    f32x4 acc[2][8];
#pragma unroll
    for (int m = 0; m < 2; ++m)
#pragma unroll
        for (int n = 0; n < 8; ++n) acc[m][n] = (f32x4)(0.f);

    const unsigned short* ta = tcat + (size_t)(rw + l15) * 192 + l4 * 8;
    bf16x8 a0 = *(const bf16x8*)(ta);
    bf16x8 a1 = *(const bf16x8*)(ta + 16 * 192);

#pragma unroll
    for (int ks = 0; ks < 6; ++ks) {
        bf16x8 na0, na1;
        if (ks < 5) {
            na0 = *(const bf16x8*)(ta + (ks + 1) * 32);
            na1 = *(const bf16x8*)(ta + 16 * 192 + (ks + 1) * 32);
        }
        const int kb = ks * 4 + l4;
#pragma unroll
        for (int nb = 0; nb < 8; ++nb) {
            const int n = nb * 16 + l15;
            const bf16x8 bv =
                *(const bf16x8*)(smem + n * 384 + ((kb ^ (n & 7)) << 4));
            acc[0][nb] = __builtin_amdgcn_mfma_f32_16x16x32_bf16(
                a0, bv, acc[0][nb], 0, 0, 0);
            acc[1][nb] = __builtin_amdgcn_mfma_f32_16x16x32_bf16(
                a1, bv, acc[1][nb], 0, 0, 0);
        }
        a0 = na0; a1 = na1;
    }
    __syncthreads();   // Bs dead

    // write h (+cheb bias) as bf16 into hS[node][c] (swizzled), smem+0..32K
#pragma unroll
    for (int mf = 0; mf < 2; ++mf)
#pragma unroll
        for (int nb = 0; nb < 8; ++nb) {
            const int c = nb * 16 + l15;
            const int slot = c >> 3;
            const float cb = cb_s[c];
#pragma unroll
            for (int reg = 0; reg < 4; ++reg) {
                const int node = wid * 32 + mf * 16 + l4 * 4 + reg;
                *(unsigned short*)(smem + node * 256 +
                                   ((slot ^ (node & 7)) << 4) + (c & 7) * 2) =
                    f2bf(acc[mf][nb][reg] + cb);
            }
        }
    // stage convW [c1][128] bf16 swizzled at smem+32768
    for (int it = 0; it < 4; ++it) {
        const int gslot = it * 256 + t;          // 0..1023
        const int c1i = gslot >> 4, q = gslot & 15;
        const bf16x8 v = *(const bf16x8*)(cvw + c1i * 128 + q * 8);
        *(bf16x8*)(smem + 32768 + c1i * 256 + ((q ^ (c1i & 7)) << 4)) = v;
    }
    __syncthreads();

    // ---- Phase B: c1 x node = convW @ h^T ----
    f32x4 acc2[8];
#pragma unroll
    for (int n = 0; n < 8; ++n) acc2[n] = (f32x4)(0.f);

#pragma unroll
    for (int ks = 0; ks < 4; ++ks) {
        const int kb = ks * 4 + l4;
        const int c1a = wid * 16 + l15;
        const bf16x8 av = *(const bf16x8*)(smem + 32768 + c1a * 256 +
                                           ((kb ^ (c1a & 7)) << 4));
#pragma unroll
        for (int nb = 0; nb < 8; ++nb) {
            const int node = nb * 16 + l15;
            const bf16x8 bv =
                *(const bf16x8*)(smem + node * 256 + ((kb ^ (node & 7)) << 4));
            acc2[nb] = __builtin_amdgcn_mfma_f32_16x16x32_bf16(
                av, bv, acc2[nb], 0, 0, 0);
        }
    }

#pragma unroll
    for (int nb = 0; nb < 8; ++nb) {
        const int ng = n0 + nb * 16 + l15;
#pragma unroll
        for (int reg = 0; reg < 4; ++reg) {
            const int c1i = wid * 16 + l4 * 4 + reg;
            cout[(size_t)bb * (C1 * NNODE) + (size_t)c1i * NNODE + ng] =
                fmaxf(acc2[nb][reg] + cvb_s[c1i], 0.f);
        }
    }
}

// ---------------------------------------------------------------------------
// Kernel 4: fc1 partials (K-split over 256-col chunks), then reduce.
// ---------------------------------------------------------------------------
__global__ __launch_bounds__(256) void k_fc1(
    const float* __restrict__ cf, const float* __restrict__ W,
    float* __restrict__ part)
{
    __shared__ float Wt[256 * 33];
    const int t = threadIdx.x;
    const int g = blockIdx.x;
    const int k0 = g * 256;

    for (int i = t; i < 8192; i += 256) {
        const int j = i >> 8, k = i & 255;
        Wt[k * 33 + j] = W[(size_t)j * (C1 * NNODE) + k0 + k];
    }
    __syncthreads();

    const int j = t & 31, bg = t >> 5;
    float acc[16];
#pragma unroll
    for (int i = 0; i < 16; ++i) acc[i] = 0.f;

    const float* cb = cf + (size_t)(bg * 16) * (C1 * NNODE) + k0;
    for (int k4 = 0; k4 < 64; ++k4) {
        const int kb = k4 * 4;
        const float w0 = Wt[(kb + 0) * 33 + j];
        const float w1 = Wt[(kb + 1) * 33 + j];
        const float w2 = Wt[(kb + 2) * 33 + j];
        const float w3 = Wt[(kb + 3) * 33 + j];
#pragma unroll
        for (int i = 0; i < 16; ++i) {
            const f32x4 cv = *(const f32x4*)&cb[(size_t)i * (C1 * NNODE) + kb];
            acc[i] += cv[0] * w0 + cv[1] * w1 + cv[2] * w2 + cv[3] * w3;
        }
    }
#pragma unroll
    for (int i = 0; i < 16; ++i)
        part[(size_t)g * 4096 + (size_t)(bg * 16 + i) * 32 + j] = acc[i];
}

__global__ __launch_bounds__(256) void k_red(
    const float* __restrict__ part, float* __restrict__ z)
{
    const int o = blockIdx.x * 256 + threadIdx.x;
    float s = 0.f;
    for (int g = 0; g < 256; ++g) s += part[(size_t)g * 4096 + o];
    z[o] = s;
}

__global__ __launch_bounds__(128) void k_head(
    const float* __restrict__ z, const float* __restrict__ b1,
    const float* __restrict__ W2, const float* __restrict__ b2,
    float* __restrict__ outp)
{
    const int b = threadIdx.x;
    float a[32];
#pragma unroll
    for (int j = 0; j < 32; ++j) a[j] = z[b * 32 + j] + b1[j];
    float l[4];
#pragma unroll
    for (int c = 0; c < 4; ++c) {
        float s = b2[c];
#pragma unroll
        for (int j = 0; j < 32; ++j) s += W2[c * 32 + j] * a[j];
        l[c] = s;
    }
    const float m = fmaxf(fmaxf(l[0], l[1]), fmaxf(l[2], l[3]));
    const float e0 = expf(l[0] - m), e1 = expf(l[1] - m);
    const float e2 = expf(l[2] - m), e3 = expf(l[3] - m);
    const float inv = 1.f / (e0 + e1 + e2 + e3);
    outp[b * 4 + 0] = e0 * inv;
    outp[b * 4 + 1] = e1 * inv;
    outp[b * 4 + 2] = e2 * inv;
    outp[b * 4 + 3] = e3 * inv;
}

// ---------------------------------------------------------------------------
extern "C" void kernel_launch(void* const* d_in, const int* in_sizes, int n_in,
                              void* d_out, int out_size, void* d_ws, size_t ws_size,
                              hipStream_t stream)
{
    const float* x     = (const float*)d_in[0];
    const int*   ei    = (const int*)d_in[1];
    const float* ew    = (const float*)d_in[2];
    const float* chebW = (const float*)d_in[3];
    const float* chebB = (const float*)d_in[4];
    const float* convW = (const float*)d_in[5];
    const float* convB = (const float*)d_in[6];
    const float* fc1W  = (const float*)d_in[7];
    const float* fc1B  = (const float*)d_in[8];
    const float* fc2W  = (const float*)d_in[9];
    const float* fc2B  = (const float*)d_in[10];
    float* out = (float*)d_out;

    char* ws = (char*)d_ws;
    float* scal = (float*)(ws + 0);
    char*  partb = ws + 8192;                      // 4MB multi-use region
    int*   cnt  = (int*)(partb + 0);
    int*   pos  = (int*)(partb + 4096);
    int*   ptr  = (int*)(partb + 8192);
    float* dgr  = (float*)(partb + 16384);
    float* dgl  = (float*)(partb + 20480);
    int2*  pk   = (int2*)(partb + 24576);          // 128KB
    unsigned short* wcatT = (unsigned short*)(partb + 262144);  // 48KB
    unsigned short* cvwB  = (unsigned short*)(partb + 327680);  // 16KB
    float* part = (float*)partb;                   // fc1 partials (after cheb)
    float* z    = (float*)(ws + 8192 + 4194304);
    float* tx1  = (float*)(ws + 8192 + 4194304 + 65536);        // 32MB
    float* cbuf = tx1;                             // alias: tx1 dead after prop2
    unsigned short* tcat = (unsigned short*)((char*)tx1 + 33554432); // 48MB

    // CSR build + weight conversion
    k_zero <<<dim3(1),  dim3(1024), 0, stream>>>(cnt, dgr, dgl);
    k_count<<<dim3(64), dim3(256),  0, stream>>>(ei, ew, cnt, dgr, dgl);
    k_scan <<<dim3(1),  dim3(1024), 0, stream>>>(cnt, ptr, pos);
    k_fill <<<dim3(64), dim3(256),  0, stream>>>(ei, ew, pos, pk);
    k_cvtw <<<dim3(128), dim3(256), 0, stream>>>(chebW, convW, wcatT, cvwB);

    k_lmax<<<dim3(1), dim3(1024), 0, stream>>>(pk, ptr, dgr, scal);

    k_prop<<<dim3(BN / 4), dim3(256), 0, stream>>>(
        x, x, pk, ptr, dgl, scal, tx1, tcat, 1, 1, 1.f, 0.f);
    k_prop<<<dim3(BN / 4), dim3(256), 0, stream>>>(
        tx1, x, pk, ptr, dgl, scal, (float*)nullptr, tcat, 2, 0, 2.f, -1.f);

    k_cheb_mfma<<<dim3(BN / 128), dim3(256), 0, stream>>>(
        tcat, wcatT, cvwB, chebB, convB, cbuf);

    k_fc1<<<dim3(256), dim3(256), 0, stream>>>(cbuf, fc1W, part);
    k_red<<<dim3(16), dim3(256), 0, stream>>>(part, z);
    k_head<<<dim3(1), dim3(128), 0, stream>>>(z, fc1B, fc2W, fc2B, out);
}

// Round 4
// 350.336 us; speedup vs baseline: 8.9151x; 1.2050x over previous
//
#include <hip/hip_runtime.h>
#include <math.h>

#define BATCH 128
#define NNODE 1024
#define EG 16384
#define F_IN 64
#define HID 128
#define C1 64
#define C2 32
#define NCLS 4
#define POWER_ITERS 50
#define BN (BATCH * NNODE)
#define RMAX 28
#define NORM_EVERY 5

typedef float f32x4 __attribute__((ext_vector_type(4)));
typedef __bf16 bf16x8 __attribute__((ext_vector_type(8)));
typedef unsigned short u16x4 __attribute__((ext_vector_type(4)));

__device__ inline unsigned short f2bf(float f) {   // round-to-nearest-even
    unsigned int u = __float_as_uint(f);
    u += 0x7fffu + ((u >> 16) & 1u);
    return (unsigned short)(u >> 16);
}
__device__ inline float bf2f(unsigned short h) {
    return __uint_as_float((unsigned int)h << 16);
}

// ---------------------------------------------------------------------------
// CSR build (by dst) in ONE single-block kernel: LDS count -> scan -> fill.
// Replaces zero/count/scan/fill (4 launches). Also emits raw/relu degree.
// ---------------------------------------------------------------------------
__global__ __launch_bounds__(1024) void k_csr(
    const int* __restrict__ ei, const float* __restrict__ ew,
    int* __restrict__ ptr_g, float* __restrict__ dgr_g,
    float* __restrict__ dgl_g, int2* __restrict__ packed)
{
    __shared__ int   cnt[NNODE];
    __shared__ float dgr[NNODE];
    __shared__ float dgl[NNODE];
    __shared__ int   s[NNODE];
    __shared__ int   base[NNODE];
    const int t = threadIdx.x;

    cnt[t] = 0; dgr[t] = 0.f; dgl[t] = 0.f;

    int es[16], ed[16];
    float w[16];
#pragma unroll
    for (int i = 0; i < 16; ++i) {
        const int e = i * 1024 + t;
        es[i] = ei[e];
        ed[i] = ei[EG + e];
        w[i]  = ew[e];
    }
    __syncthreads();
#pragma unroll
    for (int i = 0; i < 16; ++i) {
        atomicAdd(&cnt[ed[i]], 1);
        atomicAdd(&dgr[es[i]], w[i]);
        atomicAdd(&dgl[es[i]], fmaxf(w[i], 0.f));
    }
    __syncthreads();
    dgr_g[t] = dgr[t];
    dgl_g[t] = dgl[t];

    // inclusive scan (Hillis-Steele)
    const int v = cnt[t];
    s[t] = v;
    __syncthreads();
    for (int o = 1; o < 1024; o <<= 1) {
        const int add = (t >= o) ? s[t - o] : 0;
        __syncthreads();
        s[t] += add;
        __syncthreads();
    }
    const int excl = s[t] - v;
    ptr_g[t] = excl;
    base[t]  = excl;
    if (t == 1023) ptr_g[1024] = s[1023];
    __syncthreads();

#pragma unroll
    for (int i = 0; i < 16; ++i) {
        const int p = atomicAdd(&base[ed[i]], 1);
        packed[p] = make_int2(__float_as_int(w[i]), es[i]);
    }
}

// Convert/transpose weights to bf16: wcatT[n=128][k=192]; cvw[c1=64][k=128].
__global__ __launch_bounds__(256) void k_cvtw(
    const float* __restrict__ chebW, const float* __restrict__ convW,
    unsigned short* __restrict__ wcatT, unsigned short* __restrict__ cvw)
{
    const int i = blockIdx.x * 256 + threadIdx.x;
    if (i < 24576) {
        const int n = i / 192, k = i % 192;
        wcatT[i] = f2bf(chebW[k * 128 + n]);
    }
    const int j = i - 24576;
    if (j >= 0 && j < 8192) cvw[j] = f2bf(convW[j]);
}

// ---------------------------------------------------------------------------
// Kernel 1: lambda_max power iteration. Edges in REGISTERS (28 slots,
// zero-padded: pad lanes read v[0] same-address = free broadcast; rare
// deg>28 tail reads global L2). Normalization deferred to every 5th iter
// (scale-invariant; iter 49 normalized so Rayleigh quotient is unchanged).
// ---------------------------------------------------------------------------
__global__ __launch_bounds__(1024) void k_lmax(
    const int2* __restrict__ packed, const int* __restrict__ ptr,
    const float* __restrict__ deg_raw, float* __restrict__ scal)
{
    __shared__ float vA[NNODE];
    __shared__ float vB[NNODE];
    __shared__ float red[17];
    const int t = threadIdx.x;

    const int p0 = ptr[t], p1 = ptr[t + 1];
    float w[RMAX];
    int src[RMAX];
#pragma unroll
    for (int i = 0; i < RMAX; ++i) {
        if (p0 + i < p1) {
            const int2 e = packed[p0 + i];
            w[i] = __int_as_float(e.x);
            src[i] = e.y;
        } else {
            w[i] = 0.f;
            src[i] = 0;
        }
    }
    const int tp0 = p0 + RMAX;
    const float dgv = deg_raw[t];

    vA[t] = 0.03125f;   // 1/sqrt(1024)
    __syncthreads();

    float* cur = vA;
    float* nxt = vB;

    for (int it = 0; it < POWER_ITERS; ++it) {
        float u = dgv * cur[t];
#pragma unroll
        for (int i = 0; i < RMAX; ++i) u -= w[i] * cur[src[i]];
        for (int p = tp0; p < p1; ++p) {
            const int2 e = packed[p];
            u -= __int_as_float(e.x) * cur[e.y];
        }
        if ((it % NORM_EVERY) == NORM_EVERY - 1) {
            float sr = u * u;
#pragma unroll
            for (int o = 32; o > 0; o >>= 1) sr += __shfl_down(sr, o, 64);
            if ((t & 63) == 0) red[t >> 6] = sr;
            __syncthreads();
            if (t < 64) {
                float xs = (t < 16) ? red[t] : 0.f;
#pragma unroll
                for (int o = 8; o > 0; o >>= 1) xs += __shfl_down(xs, o, 64);
                if (t == 0) red[16] = 1.0f / (sqrtf(xs) + 1e-12f);
            }
            __syncthreads();
            nxt[t] = u * red[16];
        } else {
            nxt[t] = u;
        }
        __syncthreads();
        float* tmp = cur; cur = nxt; nxt = tmp;
    }

    // final matvec on the (normalized) v, then Rayleigh quotient
    float u = dgv * cur[t];
#pragma unroll
    for (int i = 0; i < RMAX; ++i) u -= w[i] * cur[src[i]];
    for (int p = tp0; p < p1; ++p) {
        const int2 e = packed[p];
        u -= __int_as_float(e.x) * cur[e.y];
    }
    float sr = cur[t] * u;
#pragma unroll
    for (int o = 32; o > 0; o >>= 1) sr += __shfl_down(sr, o, 64);
    if ((t & 63) == 0) red[t >> 6] = sr;
    __syncthreads();
    if (t == 0) {
        float lm = 0.f;
        for (int i = 0; i < 16; ++i) lm += red[i];
        scal[0] = lm;
        scal[1] = 2.0f / lm;
    }
}

// ---------------------------------------------------------------------------
// Kernel 2: out = A * lhat_mv(in) + Bc * base (gather, wave-per-node).
// 4-deep MLP on the L2 gathers. Emits bf16 slice into tcat[node][192].
// ---------------------------------------------------------------------------
__global__ __launch_bounds__(256) void k_prop(
    const float* __restrict__ in, const float* __restrict__ base,
    const int2* __restrict__ packed, const int* __restrict__ ptr,
    const float* __restrict__ deg_relu, const float* __restrict__ scal,
    float* __restrict__ out32, unsigned short* __restrict__ tcat,
    int slice, int writeX, float A, float Bc)
{
    const int bid   = ((blockIdx.x & 7) << 12) + (blockIdx.x >> 3);
    const int gnode = bid * 4 + (threadIdx.x >> 6);
    const int lane  = threadIdx.x & 63;
    const int b = gnode >> 10, d = gnode & 1023;

    const int p0 = ptr[d], p1 = ptr[d + 1];
    const float* xb = in + (size_t)b * (NNODE * F_IN);

    float acc = 0.f;
    int p = p0;
    for (; p + 4 <= p1; p += 4) {        // 4-deep MLP
        const int2 e0 = packed[p],     e1 = packed[p + 1];
        const int2 e2 = packed[p + 2], e3 = packed[p + 3];
        const float v0 = xb[(size_t)e0.y * F_IN + lane];
        const float v1 = xb[(size_t)e1.y * F_IN + lane];
        const float v2 = xb[(size_t)e2.y * F_IN + lane];
        const float v3 = xb[(size_t)e3.y * F_IN + lane];
        acc += fmaxf(__int_as_float(e0.x), 0.f) * v0;
        acc += fmaxf(__int_as_float(e1.x), 0.f) * v1;
        acc += fmaxf(__int_as_float(e2.x), 0.f) * v2;
        acc += fmaxf(__int_as_float(e3.x), 0.f) * v3;
    }
    for (; p < p1; ++p) {
        const int2 e = packed[p];
        acc += fmaxf(__int_as_float(e.x), 0.f) * xb[(size_t)e.y * F_IN + lane];
    }

    const float scale = scal[1];
    const size_t gi = (size_t)gnode * F_IN + lane;
    const float xv = in[gi];
    const float r = scale * (deg_relu[d] * xv - acc) - xv;
    float o = A * r;
    if (Bc != 0.0f) o += Bc * base[gi];
    if (out32) out32[gi] = o;
    tcat[(size_t)gnode * 192 + slice * 64 + lane] = f2bf(o);
    if (writeX) tcat[(size_t)gnode * 192 + lane] = f2bf(xv);
}

// ---------------------------------------------------------------------------
// Kernel 3: bf16 MFMA fused cheb-GEMM + conv1d. Output now bf16.
// ---------------------------------------------------------------------------
__global__ __launch_bounds__(256) void k_cheb_mfma(
    const unsigned short* __restrict__ tcat,
    const unsigned short* __restrict__ wcatT,
    const unsigned short* __restrict__ cvw,
    const float* __restrict__ chebB, const float* __restrict__ convB,
    unsigned short* __restrict__ cout)
{
    __shared__ __align__(16) char smem[49152];   // Bs (48K) / hS(32K)+cwS(16K)
    __shared__ float cb_s[HID];
    __shared__ float cvb_s[C1];

    const int t    = threadIdx.x;
    const int lane = t & 63;
    const int wid  = t >> 6;
    const int l15  = lane & 15;
    const int l4   = lane >> 4;
    const int rbase = blockIdx.x * 128;
    const int bb = rbase >> 10;
    const int n0 = rbase & 1023;

    if (t < HID) cb_s[t] = chebB[t];
    if (t < C1)  cvb_s[t] = convB[t];

    // stage W^T [n=128][k-slot 0..23] with slot XOR (n&7) swizzle
    for (int it = 0; it < 12; ++it) {
        const int gslot = it * 256 + t;          // 0..3071
        const int n = gslot / 24, q = gslot % 24;
        const bf16x8 v = *(const bf16x8*)(wcatT + n * 192 + q * 8);
        *(bf16x8*)(smem + n * 384 + ((q ^ (n & 7)) << 4)) = v;
    }
    __syncthreads();

    // ---- Phase A: 16x16x32 MFMA, A-frags straight from global ----
    const int rw = rbase + wid * 32;
    f32x4 acc[2][8];
#pragma unroll
    for (int m = 0; m < 2; ++m)
#pragma unroll
        for (int n = 0; n < 8; ++n) acc[m][n] = (f32x4)(0.f);

    const unsigned short* ta = tcat + (size_t)(rw + l15) * 192 + l4 * 8;
    bf16x8 a0 = *(const bf16x8*)(ta);
    bf16x8 a1 = *(const bf16x8*)(ta + 16 * 192);

#pragma unroll
    for (int ks = 0; ks < 6; ++ks) {
        bf16x8 na0, na1;
        if (ks < 5) {
            na0 = *(const bf16x8*)(ta + (ks + 1) * 32);
            na1 = *(const bf16x8*)(ta + 16 * 192 + (ks + 1) * 32);
        }
        const int kb = ks * 4 + l4;
#pragma unroll
        for (int nb = 0; nb < 8; ++nb) {
            const int n = nb * 16 + l15;
            const bf16x8 bv =
                *(const bf16x8*)(smem + n * 384 + ((kb ^ (n & 7)) << 4));
            acc[0][nb] = __builtin_amdgcn_mfma_f32_16x16x32_bf16(
                a0, bv, acc[0][nb], 0, 0, 0);
            acc[1][nb] = __builtin_amdgcn_mfma_f32_16x16x32_bf16(
                a1, bv, acc[1][nb], 0, 0, 0);
        }
        a0 = na0; a1 = na1;
    }
    __syncthreads();   // Bs dead

    // write h (+cheb bias) as bf16 into hS[node][c] (swizzled), smem+0..32K
#pragma unroll
    for (int mf = 0; mf < 2; ++mf)
#pragma unroll
        for (int nb = 0; nb < 8; ++nb) {
            const int c = nb * 16 + l15;
            const int slot = c >> 3;
            const float cb = cb_s[c];
#pragma unroll
            for (int reg = 0; reg < 4; ++reg) {
                const int node = wid * 32 + mf * 16 + l4 * 4 + reg;
                *(unsigned short*)(smem + node * 256 +
                                   ((slot ^ (node & 7)) << 4) + (c & 7) * 2) =
                    f2bf(acc[mf][nb][reg] + cb);
            }
        }
    // stage convW [c1][128] bf16 swizzled at smem+32768
    for (int it = 0; it < 4; ++it) {
        const int gslot = it * 256 + t;          // 0..1023
        const int c1i = gslot >> 4, q = gslot & 15;
        const bf16x8 v = *(const bf16x8*)(cvw + c1i * 128 + q * 8);
        *(bf16x8*)(smem + 32768 + c1i * 256 + ((q ^ (c1i & 7)) << 4)) = v;
    }
    __syncthreads();

    // ---- Phase B: c1 x node = convW @ h^T ----
    f32x4 acc2[8];
#pragma unroll
    for (int n = 0; n < 8; ++n) acc2[n] = (f32x4)(0.f);

#pragma unroll
    for (int ks = 0; ks < 4; ++ks) {
        const int kb = ks * 4 + l4;
        const int c1a = wid * 16 + l15;
        const bf16x8 av = *(const bf16x8*)(smem + 32768 + c1a * 256 +
                                           ((kb ^ (c1a & 7)) << 4));
#pragma unroll
        for (int nb = 0; nb < 8; ++nb) {
            const int node = nb * 16 + l15;
            const bf16x8 bv =
                *(const bf16x8*)(smem + node * 256 + ((kb ^ (node & 7)) << 4));
            acc2[nb] = __builtin_amdgcn_mfma_f32_16x16x32_bf16(
                av, bv, acc2[nb], 0, 0, 0);
        }
    }

#pragma unroll
    for (int nb = 0; nb < 8; ++nb) {
        const int ng = n0 + nb * 16 + l15;
#pragma unroll
        for (int reg = 0; reg < 4; ++reg) {
            const int c1i = wid * 16 + l4 * 4 + reg;
            cout[(size_t)bb * (C1 * NNODE) + (size_t)c1i * NNODE + ng] =
                f2bf(fmaxf(acc2[nb][reg] + cvb_s[c1i], 0.f));
        }
    }
}

// ---------------------------------------------------------------------------
// Kernel 4: fc1 partials (K-split over 256-col chunks), bf16 input.
// ---------------------------------------------------------------------------
__global__ __launch_bounds__(256) void k_fc1(
    const unsigned short* __restrict__ cf, const float* __restrict__ W,
    float* __restrict__ part)
{
    __shared__ float Wt[256 * 33];
    const int t = threadIdx.x;
    const int g = blockIdx.x;
    const int k0 = g * 256;

    for (int i = t; i < 8192; i += 256) {
        const int j = i >> 8, k = i & 255;
        Wt[k * 33 + j] = W[(size_t)j * (C1 * NNODE) + k0 + k];
    }
    __syncthreads();

    const int j = t & 31, bg = t >> 5;
    float acc[16];
#pragma unroll
    for (int i = 0; i < 16; ++i) acc[i] = 0.f;

    const unsigned short* cb = cf + (size_t)(bg * 16) * (C1 * NNODE) + k0;
    for (int k4 = 0; k4 < 64; ++k4) {
        const int kb = k4 * 4;
        const float w0 = Wt[(kb + 0) * 33 + j];
        const float w1 = Wt[(kb + 1) * 33 + j];
        const float w2 = Wt[(kb + 2) * 33 + j];
        const float w3 = Wt[(kb + 3) * 33 + j];
#pragma unroll
        for (int i = 0; i < 16; ++i) {
            const u16x4 cv = *(const u16x4*)&cb[(size_t)i * (C1 * NNODE) + kb];
            acc[i] += bf2f(cv[0]) * w0 + bf2f(cv[1]) * w1 +
                      bf2f(cv[2]) * w2 + bf2f(cv[3]) * w3;
        }
    }
#pragma unroll
    for (int i = 0; i < 16; ++i)
        part[(size_t)g * 4096 + (size_t)(bg * 16 + i) * 32 + j] = acc[i];
}

__global__ __launch_bounds__(256) void k_red(
    const float* __restrict__ part, float* __restrict__ z)
{
    const int o = blockIdx.x * 256 + threadIdx.x;
    float s = 0.f;
    for (int g = 0; g < 256; ++g) s += part[(size_t)g * 4096 + o];
    z[o] = s;
}

__global__ __launch_bounds__(128) void k_head(
    const float* __restrict__ z, const float* __restrict__ b1,
    const float* __restrict__ W2, const float* __restrict__ b2,
    float* __restrict__ outp)
{
    const int b = threadIdx.x;
    float a[32];
#pragma unroll
    for (int j = 0; j < 32; ++j) a[j] = z[b * 32 + j] + b1[j];
    float l[4];
#pragma unroll
    for (int c = 0; c < 4; ++c) {
        float s = b2[c];
#pragma unroll
        for (int j = 0; j < 32; ++j) s += W2[c * 32 + j] * a[j];
        l[c] = s;
    }
    const float m = fmaxf(fmaxf(l[0], l[1]), fmaxf(l[2], l[3]));
    const float e0 = expf(l[0] - m), e1 = expf(l[1] - m);
    const float e2 = expf(l[2] - m), e3 = expf(l[3] - m);
    const float inv = 1.f / (e0 + e1 + e2 + e3);
    outp[b * 4 + 0] = e0 * inv;
    outp[b * 4 + 1] = e1 * inv;
    outp[b * 4 + 2] = e2 * inv;
    outp[b * 4 + 3] = e3 * inv;
}

// ---------------------------------------------------------------------------
extern "C" void kernel_launch(void* const* d_in, const int* in_sizes, int n_in,
                              void* d_out, int out_size, void* d_ws, size_t ws_size,
                              hipStream_t stream)
{
    const float* x     = (const float*)d_in[0];
    const int*   ei    = (const int*)d_in[1];
    const float* ew    = (const float*)d_in[2];
    const float* chebW = (const float*)d_in[3];
    const float* chebB = (const float*)d_in[4];
    const float* convW = (const float*)d_in[5];
    const float* convB = (const float*)d_in[6];
    const float* fc1W  = (const float*)d_in[7];
    const float* fc1B  = (const float*)d_in[8];
    const float* fc2W  = (const float*)d_in[9];
    const float* fc2B  = (const float*)d_in[10];
    float* out = (float*)d_out;

    char* ws = (char*)d_ws;
    float* scal = (float*)(ws + 0);
    char*  partb = ws + 8192;                      // 4MB multi-use region
    int*   ptr  = (int*)(partb + 8192);
    float* dgr  = (float*)(partb + 16384);
    float* dgl  = (float*)(partb + 20480);
    int2*  pk   = (int2*)(partb + 24576);          // 128KB
    unsigned short* wcatT = (unsigned short*)(partb + 262144);  // 48KB
    unsigned short* cvwB  = (unsigned short*)(partb + 327680);  // 16KB
    float* part = (float*)partb;                   // fc1 partials (after cheb)
    float* z    = (float*)(ws + 8192 + 4194304);
    float* tx1  = (float*)(ws + 8192 + 4194304 + 65536);        // 32MB
    unsigned short* tcat = (unsigned short*)((char*)tx1 + 33554432); // 48MB
    unsigned short* cbuf = (unsigned short*)((char*)tcat + 50331648); // 16MB

    k_csr <<<dim3(1),   dim3(1024), 0, stream>>>(ei, ew, ptr, dgr, dgl, pk);
    k_cvtw<<<dim3(128), dim3(256),  0, stream>>>(chebW, convW, wcatT, cvwB);

    k_lmax<<<dim3(1), dim3(1024), 0, stream>>>(pk, ptr, dgr, scal);

    k_prop<<<dim3(BN / 4), dim3(256), 0, stream>>>(
        x, x, pk, ptr, dgl, scal, tx1, tcat, 1, 1, 1.f, 0.f);
    k_prop<<<dim3(BN / 4), dim3(256), 0, stream>>>(
        tx1, x, pk, ptr, dgl, scal, (float*)nullptr, tcat, 2, 0, 2.f, -1.f);

    k_cheb_mfma<<<dim3(BN / 128), dim3(256), 0, stream>>>(
        tcat, wcatT, cvwB, chebB, convB, cbuf);

    k_fc1<<<dim3(256), dim3(256), 0, stream>>>(cbuf, fc1W, part);
    k_red<<<dim3(16), dim3(256), 0, stream>>>(part, z);
    k_head<<<dim3(1), dim3(128), 0, stream>>>(z, fc1B, fc2W, fc2B, out);
}

// Round 5
// 304.622 us; speedup vs baseline: 10.2530x; 1.1501x over previous
//
#include <hip/hip_runtime.h>
#include <math.h>

#define BATCH 128
#define NNODE 1024
#define EG 16384
#define F_IN 64
#define HID 128
#define C1 64
#define C2 32
#define NCLS 4
#define POWER_ITERS 50
#define BN (BATCH * NNODE)
#define RMAX 28
#define NORM_EVERY 5

typedef float f32x4 __attribute__((ext_vector_type(4)));
typedef __bf16 bf16x8 __attribute__((ext_vector_type(8)));
typedef unsigned short u16x4 __attribute__((ext_vector_type(4)));

__device__ inline unsigned short f2bf(float f) {   // round-to-nearest-even
    unsigned int u = __float_as_uint(f);
    u += 0x7fffu + ((u >> 16) & 1u);
    return (unsigned short)(u >> 16);
}
__device__ inline float bf2f(unsigned short h) {
    return __uint_as_float((unsigned int)h << 16);
}

// ---------------------------------------------------------------------------
// CSR build (by dst) in ONE single-block kernel: LDS count -> scan -> fill.
// Emits pk  {raw_w, src}        for k_lmax (register preload),
//       pk2 {relu_w, src*256}   for k_prop (scalar-pipe edge stream).
// ---------------------------------------------------------------------------
__global__ __launch_bounds__(1024) void k_csr(
    const int* __restrict__ ei, const float* __restrict__ ew,
    int* __restrict__ ptr_g, float* __restrict__ dgr_g,
    float* __restrict__ dgl_g, int2* __restrict__ packed,
    int2* __restrict__ packed2)
{
    __shared__ int   cnt[NNODE];
    __shared__ float dgr[NNODE];
    __shared__ float dgl[NNODE];
    __shared__ int   s[NNODE];
    __shared__ int   base[NNODE];
    const int t = threadIdx.x;

    cnt[t] = 0; dgr[t] = 0.f; dgl[t] = 0.f;

    int es[16], ed[16];
    float w[16];
#pragma unroll
    for (int i = 0; i < 16; ++i) {
        const int e = i * 1024 + t;
        es[i] = ei[e];
        ed[i] = ei[EG + e];
        w[i]  = ew[e];
    }
    __syncthreads();
#pragma unroll
    for (int i = 0; i < 16; ++i) {
        atomicAdd(&cnt[ed[i]], 1);
        atomicAdd(&dgr[es[i]], w[i]);
        atomicAdd(&dgl[es[i]], fmaxf(w[i], 0.f));
    }
    __syncthreads();
    dgr_g[t] = dgr[t];
    dgl_g[t] = dgl[t];

    // inclusive scan (Hillis-Steele)
    const int v = cnt[t];
    s[t] = v;
    __syncthreads();
    for (int o = 1; o < 1024; o <<= 1) {
        const int add = (t >= o) ? s[t - o] : 0;
        __syncthreads();
        s[t] += add;
        __syncthreads();
    }
    const int excl = s[t] - v;
    ptr_g[t] = excl;
    base[t]  = excl;
    if (t == 1023) ptr_g[1024] = s[1023];
    __syncthreads();

#pragma unroll
    for (int i = 0; i < 16; ++i) {
        const int p = atomicAdd(&base[ed[i]], 1);
        packed[p]  = make_int2(__float_as_int(w[i]), es[i]);
        packed2[p] = make_int2(__float_as_int(fmaxf(w[i], 0.f)), es[i] << 8);
    }
}

// Convert/transpose weights to bf16: wcatT[n=128][k=192]; cvw[c1=64][k=128].
__global__ __launch_bounds__(256) void k_cvtw(
    const float* __restrict__ chebW, const float* __restrict__ convW,
    unsigned short* __restrict__ wcatT, unsigned short* __restrict__ cvw)
{
    const int i = blockIdx.x * 256 + threadIdx.x;
    if (i < 24576) {
        const int n = i / 192, k = i % 192;
        wcatT[i] = f2bf(chebW[k * 128 + n]);
    }
    const int j = i - 24576;
    if (j >= 0 && j < 8192) cvw[j] = f2bf(convW[j]);
}

// ---------------------------------------------------------------------------
// Kernel 1: lambda_max power iteration. Edges in registers (28 slots,
// zero-padded). Normalization deferred to every 5th iteration.
// ---------------------------------------------------------------------------
__global__ __launch_bounds__(1024) void k_lmax(
    const int2* __restrict__ packed, const int* __restrict__ ptr,
    const float* __restrict__ deg_raw, float* __restrict__ scal)
{
    __shared__ float vA[NNODE];
    __shared__ float vB[NNODE];
    __shared__ float red[17];
    const int t = threadIdx.x;

    const int p0 = ptr[t], p1 = ptr[t + 1];
    float w[RMAX];
    int src[RMAX];
#pragma unroll
    for (int i = 0; i < RMAX; ++i) {
        if (p0 + i < p1) {
            const int2 e = packed[p0 + i];
            w[i] = __int_as_float(e.x);
            src[i] = e.y;
        } else {
            w[i] = 0.f;
            src[i] = 0;
        }
    }
    const int tp0 = p0 + RMAX;
    const float dgv = deg_raw[t];

    vA[t] = 0.03125f;   // 1/sqrt(1024)
    __syncthreads();

    float* cur = vA;
    float* nxt = vB;

    for (int it = 0; it < POWER_ITERS; ++it) {
        float u = dgv * cur[t];
#pragma unroll
        for (int i = 0; i < RMAX; ++i) u -= w[i] * cur[src[i]];
        for (int p = tp0; p < p1; ++p) {
            const int2 e = packed[p];
            u -= __int_as_float(e.x) * cur[e.y];
        }
        if ((it % NORM_EVERY) == NORM_EVERY - 1) {
            float sr = u * u;
#pragma unroll
            for (int o = 32; o > 0; o >>= 1) sr += __shfl_down(sr, o, 64);
            if ((t & 63) == 0) red[t >> 6] = sr;
            __syncthreads();
            if (t < 64) {
                float xs = (t < 16) ? red[t] : 0.f;
#pragma unroll
                for (int o = 8; o > 0; o >>= 1) xs += __shfl_down(xs, o, 64);
                if (t == 0) red[16] = 1.0f / (sqrtf(xs) + 1e-12f);
            }
            __syncthreads();
            nxt[t] = u * red[16];
        } else {
            nxt[t] = u;
        }
        __syncthreads();
        float* tmp = cur; cur = nxt; nxt = tmp;
    }

    float u = dgv * cur[t];
#pragma unroll
    for (int i = 0; i < RMAX; ++i) u -= w[i] * cur[src[i]];
    for (int p = tp0; p < p1; ++p) {
        const int2 e = packed[p];
        u -= __int_as_float(e.x) * cur[e.y];
    }
    float sr = cur[t] * u;
#pragma unroll
    for (int o = 32; o > 0; o >>= 1) sr += __shfl_down(sr, o, 64);
    if ((t & 63) == 0) red[t >> 6] = sr;
    __syncthreads();
    if (t == 0) {
        float lm = 0.f;
        for (int i = 0; i < 16; ++i) lm += red[i];
        scal[0] = lm;
        scal[1] = 2.0f / lm;
    }
}

// ---------------------------------------------------------------------------
// Kernel 2: out = A * lhat_mv(in) + Bc * base, gather via pk2 {relu_w, src*256}.
// Wave-per-node; ALL edge data flows through the scalar pipe (readfirstlane
// forces wave-uniform p0/p1/row pointers -> s_load + SGPR-base gathers).
// Per-edge VALU: one fmac with SGPR weight. 4-deep unroll for latency.
// ---------------------------------------------------------------------------
__global__ __launch_bounds__(256) void k_prop(
    const float* __restrict__ in, const float* __restrict__ base,
    const int2* __restrict__ pk2, const int* __restrict__ ptrg,
    const float* __restrict__ deg_relu, const float* __restrict__ scal,
    float* __restrict__ out32, unsigned short* __restrict__ tcat,
    int slice, int writeX, float A, float Bc)
{
    const int bid  = ((blockIdx.x & 7) << 12) + (blockIdx.x >> 3);
    const int lane = threadIdx.x & 63;
    const int gnode = __builtin_amdgcn_readfirstlane(bid * 4 + (threadIdx.x >> 6));
    const int b = gnode >> 10, d = gnode & 1023;

    const int p0 = __builtin_amdgcn_readfirstlane(ptrg[d]);
    const int p1 = __builtin_amdgcn_readfirstlane(ptrg[d + 1]);
    const char* xb = (const char*)(in + (size_t)b * (NNODE * F_IN));

    float acc = 0.f;
    int p = p0;
    for (; p + 4 <= p1; p += 4) {
        const int2 e0 = pk2[p],     e1 = pk2[p + 1];
        const int2 e2 = pk2[p + 2], e3 = pk2[p + 3];
        const float* r0 = (const float*)(xb + (unsigned)e0.y);
        const float* r1 = (const float*)(xb + (unsigned)e1.y);
        const float* r2 = (const float*)(xb + (unsigned)e2.y);
        const float* r3 = (const float*)(xb + (unsigned)e3.y);
        const float v0 = r0[lane];
        const float v1 = r1[lane];
        const float v2 = r2[lane];
        const float v3 = r3[lane];
        acc += __int_as_float(e0.x) * v0;
        acc += __int_as_float(e1.x) * v1;
        acc += __int_as_float(e2.x) * v2;
        acc += __int_as_float(e3.x) * v3;
    }
    for (; p < p1; ++p) {
        const int2 e = pk2[p];
        const float* r = (const float*)(xb + (unsigned)e.y);
        acc += __int_as_float(e.x) * r[lane];
    }

    const float scale = scal[1];
    const size_t gi = (size_t)gnode * F_IN + lane;
    const float xv = in[gi];
    const float r = scale * (deg_relu[d] * xv - acc) - xv;
    float o = A * r;
    if (Bc != 0.0f) o += Bc * base[gi];
    if (out32) out32[gi] = o;
    tcat[(size_t)gnode * 192 + slice * 64 + lane] = f2bf(o);
    if (writeX) tcat[(size_t)gnode * 192 + lane] = f2bf(xv);
}

// ---------------------------------------------------------------------------
// Kernel 3: bf16 MFMA fused cheb-GEMM + conv1d. Output bf16.
// ---------------------------------------------------------------------------
__global__ __launch_bounds__(256) void k_cheb_mfma(
    const unsigned short* __restrict__ tcat,
    const unsigned short* __restrict__ wcatT,
    const unsigned short* __restrict__ cvw,
    const float* __restrict__ chebB, const float* __restrict__ convB,
    unsigned short* __restrict__ cout)
{
    __shared__ __align__(16) char smem[49152];   // Bs (48K) / hS(32K)+cwS(16K)
    __shared__ float cb_s[HID];
    __shared__ float cvb_s[C1];

    const int t    = threadIdx.x;
    const int lane = t & 63;
    const int wid  = t >> 6;
    const int l15  = lane & 15;
    const int l4   = lane >> 4;
    const int rbase = blockIdx.x * 128;
    const int bb = rbase >> 10;
    const int n0 = rbase & 1023;

    if (t < HID) cb_s[t] = chebB[t];
    if (t < C1)  cvb_s[t] = convB[t];

    // stage W^T [n=128][k-slot 0..23] with slot XOR (n&7) swizzle
    for (int it = 0; it < 12; ++it) {
        const int gslot = it * 256 + t;          // 0..3071
        const int n = gslot / 24, q = gslot % 24;
        const bf16x8 v = *(const bf16x8*)(wcatT + n * 192 + q * 8);
        *(bf16x8*)(smem + n * 384 + ((q ^ (n & 7)) << 4)) = v;
    }
    __syncthreads();

    // ---- Phase A: 16x16x32 MFMA, A-frags straight from global ----
    const int rw = rbase + wid * 32;
    f32x4 acc[2][8];
#pragma unroll
    for (int m = 0; m < 2; ++m)
#pragma unroll
        for (int n = 0; n < 8; ++n) acc[m][n] = (f32x4)(0.f);

    const unsigned short* ta = tcat + (size_t)(rw + l15) * 192 + l4 * 8;
    bf16x8 a0 = *(const bf16x8*)(ta);
    bf16x8 a1 = *(const bf16x8*)(ta + 16 * 192);

#pragma unroll
    for (int ks = 0; ks < 6; ++ks) {
        bf16x8 na0, na1;
        if (ks < 5) {
            na0 = *(const bf16x8*)(ta + (ks + 1) * 32);
            na1 = *(const bf16x8*)(ta + 16 * 192 + (ks + 1) * 32);
        }
        const int kb = ks * 4 + l4;
#pragma unroll
        for (int nb = 0; nb < 8; ++nb) {
            const int n = nb * 16 + l15;
            const bf16x8 bv =
                *(const bf16x8*)(smem + n * 384 + ((kb ^ (n & 7)) << 4));
            acc[0][nb] = __builtin_amdgcn_mfma_f32_16x16x32_bf16(
                a0, bv, acc[0][nb], 0, 0, 0);
            acc[1][nb] = __builtin_amdgcn_mfma_f32_16x16x32_bf16(
                a1, bv, acc[1][nb], 0, 0, 0);
        }
        a0 = na0; a1 = na1;
    }
    __syncthreads();   // Bs dead

    // write h (+cheb bias) as bf16 into hS[node][c] (swizzled), smem+0..32K
#pragma unroll
    for (int mf = 0; mf < 2; ++mf)
#pragma unroll
        for (int nb = 0; nb < 8; ++nb) {
            const int c = nb * 16 + l15;
            const int slot = c >> 3;
            const float cb = cb_s[c];
#pragma unroll
            for (int reg = 0; reg < 4; ++reg) {
                const int node = wid * 32 + mf * 16 + l4 * 4 + reg;
                *(unsigned short*)(smem + node * 256 +
                                   ((slot ^ (node & 7)) << 4) + (c & 7) * 2) =
                    f2bf(acc[mf][nb][reg] + cb);
            }
        }
    // stage convW [c1][128] bf16 swizzled at smem+32768
    for (int it = 0; it < 4; ++it) {
        const int gslot = it * 256 + t;          // 0..1023
        const int c1i = gslot >> 4, q = gslot & 15;
        const bf16x8 v = *(const bf16x8*)(cvw + c1i * 128 + q * 8);
        *(bf16x8*)(smem + 32768 + c1i * 256 + ((q ^ (c1i & 7)) << 4)) = v;
    }
    __syncthreads();

    // ---- Phase B: c1 x node = convW @ h^T ----
    f32x4 acc2[8];
#pragma unroll
    for (int n = 0; n < 8; ++n) acc2[n] = (f32x4)(0.f);

#pragma unroll
    for (int ks = 0; ks < 4; ++ks) {
        const int kb = ks * 4 + l4;
        const int c1a = wid * 16 + l15;
        const bf16x8 av = *(const bf16x8*)(smem + 32768 + c1a * 256 +
                                           ((kb ^ (c1a & 7)) << 4));
#pragma unroll
        for (int nb = 0; nb < 8; ++nb) {
            const int node = nb * 16 + l15;
            const bf16x8 bv =
                *(const bf16x8*)(smem + node * 256 + ((kb ^ (node & 7)) << 4));
            acc2[nb] = __builtin_amdgcn_mfma_f32_16x16x32_bf16(
                av, bv, acc2[nb], 0, 0, 0);
        }
    }

#pragma unroll
    for (int nb = 0; nb < 8; ++nb) {
        const int ng = n0 + nb * 16 + l15;
#pragma unroll
        for (int reg = 0; reg < 4; ++reg) {
            const int c1i = wid * 16 + l4 * 4 + reg;
            cout[(size_t)bb * (C1 * NNODE) + (size_t)c1i * NNODE + ng] =
                f2bf(fmaxf(acc2[nb][reg] + cvb_s[c1i], 0.f));
        }
    }
}

// ---------------------------------------------------------------------------
// Kernel 4: fc1 partials (K-split over 256-col chunks), bf16 input.
// ---------------------------------------------------------------------------
__global__ __launch_bounds__(256) void k_fc1(
    const unsigned short* __restrict__ cf, const float* __restrict__ W,
    float* __restrict__ part)
{
    __shared__ float Wt[256 * 33];
    const int t = threadIdx.x;
    const int g = blockIdx.x;
    const int k0 = g * 256;

    for (int i = t; i < 8192; i += 256) {
        const int j = i >> 8, k = i & 255;
        Wt[k * 33 + j] = W[(size_t)j * (C1 * NNODE) + k0 + k];
    }
    __syncthreads();

    const int j = t & 31, bg = t >> 5;
    float acc[16];
#pragma unroll
    for (int i = 0; i < 16; ++i) acc[i] = 0.f;

    const unsigned short* cb = cf + (size_t)(bg * 16) * (C1 * NNODE) + k0;
    for (int k4 = 0; k4 < 64; ++k4) {
        const int kb = k4 * 4;
        const float w0 = Wt[(kb + 0) * 33 + j];
        const float w1 = Wt[(kb + 1) * 33 + j];
        const float w2 = Wt[(kb + 2) * 33 + j];
        const float w3 = Wt[(kb + 3) * 33 + j];
#pragma unroll
        for (int i = 0; i < 16; ++i) {
            const u16x4 cv = *(const u16x4*)&cb[(size_t)i * (C1 * NNODE) + kb];
            acc[i] += bf2f(cv[0]) * w0 + bf2f(cv[1]) * w1 +
                      bf2f(cv[2]) * w2 + bf2f(cv[3]) * w3;
        }
    }
#pragma unroll
    for (int i = 0; i < 16; ++i)
        part[(size_t)g * 4096 + (size_t)(bg * 16 + i) * 32 + j] = acc[i];
}

__global__ __launch_bounds__(256) void k_red(
    const float* __restrict__ part, float* __restrict__ z)
{
    const int o = blockIdx.x * 256 + threadIdx.x;
    float s = 0.f;
    for (int g = 0; g < 256; ++g) s += part[(size_t)g * 4096 + o];
    z[o] = s;
}

__global__ __launch_bounds__(128) void k_head(
    const float* __restrict__ z, const float* __restrict__ b1,
    const float* __restrict__ W2, const float* __restrict__ b2,
    float* __restrict__ outp)
{
    const int b = threadIdx.x;
    float a[32];
#pragma unroll
    for (int j = 0; j < 32; ++j) a[j] = z[b * 32 + j] + b1[j];
    float l[4];
#pragma unroll
    for (int c = 0; c < 4; ++c) {
        float s = b2[c];
#pragma unroll
        for (int j = 0; j < 32; ++j) s += W2[c * 32 + j] * a[j];
        l[c] = s;
    }
    const float m = fmaxf(fmaxf(l[0], l[1]), fmaxf(l[2], l[3]));
    const float e0 = expf(l[0] - m), e1 = expf(l[1] - m);
    const float e2 = expf(l[2] - m), e3 = expf(l[3] - m);
    const float inv = 1.f / (e0 + e1 + e2 + e3);
    outp[b * 4 + 0] = e0 * inv;
    outp[b * 4 + 1] = e1 * inv;
    outp[b * 4 + 2] = e2 * inv;
    outp[b * 4 + 3] = e3 * inv;
}

// ---------------------------------------------------------------------------
extern "C" void kernel_launch(void* const* d_in, const int* in_sizes, int n_in,
                              void* d_out, int out_size, void* d_ws, size_t ws_size,
                              hipStream_t stream)
{
    const float* x     = (const float*)d_in[0];
    const int*   ei    = (const int*)d_in[1];
    const float* ew    = (const float*)d_in[2];
    const float* chebW = (const float*)d_in[3];
    const float* chebB = (const float*)d_in[4];
    const float* convW = (const float*)d_in[5];
    const float* convB = (const float*)d_in[6];
    const float* fc1W  = (const float*)d_in[7];
    const float* fc1B  = (const float*)d_in[8];
    const float* fc2W  = (const float*)d_in[9];
    const float* fc2B  = (const float*)d_in[10];
    float* out = (float*)d_out;

    char* ws = (char*)d_ws;
    float* scal = (float*)(ws + 0);
    char*  partb = ws + 8192;                      // 4MB multi-use region
    int*   ptr  = (int*)(partb + 8192);
    float* dgr  = (float*)(partb + 16384);
    float* dgl  = (float*)(partb + 20480);
    int2*  pk   = (int2*)(partb + 24576);          // 128KB (raw w, src)
    unsigned short* wcatT = (unsigned short*)(partb + 262144);  // 48KB
    unsigned short* cvwB  = (unsigned short*)(partb + 327680);  // 16KB
    int2*  pk2  = (int2*)(partb + 458752);         // 128KB (relu w, src*256)
    float* part = (float*)partb;                   // fc1 partials (after cheb)
    float* z    = (float*)(ws + 8192 + 4194304);
    float* tx1  = (float*)(ws + 8192 + 4194304 + 65536);        // 32MB
    unsigned short* tcat = (unsigned short*)((char*)tx1 + 33554432); // 48MB
    unsigned short* cbuf = (unsigned short*)((char*)tcat + 50331648); // 16MB

    k_csr <<<dim3(1),   dim3(1024), 0, stream>>>(ei, ew, ptr, dgr, dgl, pk, pk2);
    k_cvtw<<<dim3(128), dim3(256),  0, stream>>>(chebW, convW, wcatT, cvwB);

    k_lmax<<<dim3(1), dim3(1024), 0, stream>>>(pk, ptr, dgr, scal);

    k_prop<<<dim3(BN / 4), dim3(256), 0, stream>>>(
        x, x, pk2, ptr, dgl, scal, tx1, tcat, 1, 1, 1.f, 0.f);
    k_prop<<<dim3(BN / 4), dim3(256), 0, stream>>>(
        tx1, x, pk2, ptr, dgl, scal, (float*)nullptr, tcat, 2, 0, 2.f, -1.f);

    k_cheb_mfma<<<dim3(BN / 128), dim3(256), 0, stream>>>(
        tcat, wcatT, cvwB, chebB, convB, cbuf);

    k_fc1<<<dim3(256), dim3(256), 0, stream>>>(cbuf, fc1W, part);
    k_red<<<dim3(16), dim3(256), 0, stream>>>(part, z);
    k_head<<<dim3(1), dim3(128), 0, stream>>>(z, fc1B, fc2W, fc2B, out);
}

// Round 6
// 268.040 us; speedup vs baseline: 11.6523x; 1.1365x over previous
//
#include <hip/hip_runtime.h>
#include <math.h>

#define BATCH 128
#define NNODE 1024
#define EG 16384
#define F_IN 64
#define HID 128
#define C1 64
#define C2 32
#define NCLS 4
#define POWER_ITERS 50
#define BN (BATCH * NNODE)
#define RMAX 28
#define NORM_EVERY 5

typedef float f32x4 __attribute__((ext_vector_type(4)));
typedef __bf16 bf16x8 __attribute__((ext_vector_type(8)));
typedef unsigned short u16x4 __attribute__((ext_vector_type(4)));

__device__ inline unsigned short f2bf(float f) {   // round-to-nearest-even
    unsigned int u = __float_as_uint(f);
    u += 0x7fffu + ((u >> 16) & 1u);
    return (unsigned short)(u >> 16);
}
__device__ inline float bf2f(unsigned short h) {
    return __uint_as_float((unsigned int)h << 16);
}

// ---------------------------------------------------------------------------
// CSR build (by dst) in ONE single-block kernel: LDS count -> scan -> fill.
// Emits pk  {raw_w, src}        for lmax (block-0 path of k_fused),
//       pk2 {relu_w, src*256}   for the prop path (scalar-pipe edge stream).
// ---------------------------------------------------------------------------
__global__ __launch_bounds__(1024) void k_csr(
    const int* __restrict__ ei, const float* __restrict__ ew,
    int* __restrict__ ptr_g, float* __restrict__ dgr_g,
    float* __restrict__ dgl_g, int2* __restrict__ packed,
    int2* __restrict__ packed2)
{
    __shared__ int   cnt[NNODE];
    __shared__ float dgr[NNODE];
    __shared__ float dgl[NNODE];
    __shared__ int   s[NNODE];
    __shared__ int   base[NNODE];
    const int t = threadIdx.x;

    cnt[t] = 0; dgr[t] = 0.f; dgl[t] = 0.f;

    int es[16], ed[16];
    float w[16];
#pragma unroll
    for (int i = 0; i < 16; ++i) {
        const int e = i * 1024 + t;
        es[i] = ei[e];
        ed[i] = ei[EG + e];
        w[i]  = ew[e];
    }
    __syncthreads();
#pragma unroll
    for (int i = 0; i < 16; ++i) {
        atomicAdd(&cnt[ed[i]], 1);
        atomicAdd(&dgr[es[i]], w[i]);
        atomicAdd(&dgl[es[i]], fmaxf(w[i], 0.f));
    }
    __syncthreads();
    dgr_g[t] = dgr[t];
    dgl_g[t] = dgl[t];

    const int v = cnt[t];
    s[t] = v;
    __syncthreads();
    for (int o = 1; o < 1024; o <<= 1) {
        const int add = (t >= o) ? s[t - o] : 0;
        __syncthreads();
        s[t] += add;
        __syncthreads();
    }
    const int excl = s[t] - v;
    ptr_g[t] = excl;
    base[t]  = excl;
    if (t == 1023) ptr_g[1024] = s[1023];
    __syncthreads();

#pragma unroll
    for (int i = 0; i < 16; ++i) {
        const int p = atomicAdd(&base[ed[i]], 1);
        packed[p]  = make_int2(__float_as_int(w[i]), es[i]);
        packed2[p] = make_int2(__float_as_int(fmaxf(w[i], 0.f)), es[i] << 8);
    }
}

// ---------------------------------------------------------------------------
// Weight conversion WITH lambda-scale folding (runs after lmax finishes):
//   h = x(W0-W1+W2) + y1*s(W1-4W2) + y2*2s^2*W2,  y1=Lx, y2=L^2 x, s=2/lmax.
// wcatT[n=128][kk=192] bf16; cvw[c1=64][k=128] bf16 (unscaled).
// ---------------------------------------------------------------------------
__global__ __launch_bounds__(256) void k_cvtw(
    const float* __restrict__ chebW, const float* __restrict__ convW,
    const float* __restrict__ scal,
    unsigned short* __restrict__ wcatT, unsigned short* __restrict__ cvw)
{
    const int i = blockIdx.x * 256 + threadIdx.x;
    const float s = scal[1];
    if (i < 24576) {
        const int n = i / 192, kk = i % 192;
        const int k = kk & 63;
        const float w0 = chebW[k * 128 + n];
        const float w1 = chebW[8192 + k * 128 + n];
        const float w2 = chebW[16384 + k * 128 + n];
        float val;
        if (kk < 64)       val = w0 - w1 + w2;
        else if (kk < 128) val = s * (w1 - 4.f * w2);
        else               val = 2.f * s * s * w2;
        wcatT[i] = f2bf(val);
    }
    const int j = i - 24576;
    if (j >= 0 && j < 8192) cvw[j] = f2bf(convW[j]);
}

// ---------------------------------------------------------------------------
// Fused kernel: block 0 runs lmax power-iteration chunk [it0,it1) (+Rayleigh
// if finalize); blocks 1..8192 compute y = L(in) = deg_relu .* in - agg(in),
// one wave per node, edge stream on the scalar pipe. lmax (~39us/half) hides
// under the prop phase (~60us) -> lmax off the critical path.
// ---------------------------------------------------------------------------
__global__ __launch_bounds__(1024) void k_fused(
    const float* __restrict__ in,
    const int2* __restrict__ pk_raw, const int2* __restrict__ pk2,
    const int* __restrict__ ptrg,
    const float* __restrict__ dgr, const float* __restrict__ dgl,
    float* __restrict__ vstate, float* __restrict__ scal,
    float* __restrict__ out32, unsigned short* __restrict__ tcat,
    int slice, int writeX, int it0, int it1, int finalize)
{
    __shared__ float vA[NNODE];
    __shared__ float vB[NNODE];
    __shared__ float red[17];
    const int t = threadIdx.x;

    if (blockIdx.x == 0) {
        // ---------------- lambda_max partial power iteration ----------------
        const int p0 = ptrg[t], p1 = ptrg[t + 1];
        float w[RMAX];
        int src[RMAX];
#pragma unroll
        for (int i = 0; i < RMAX; ++i) {
            if (p0 + i < p1) {
                const int2 e = pk_raw[p0 + i];
                w[i] = __int_as_float(e.x);
                src[i] = e.y;
            } else {
                w[i] = 0.f;
                src[i] = 0;
            }
        }
        const int tp0 = p0 + RMAX;
        const float dgv = dgr[t];

        vA[t] = (it0 == 0) ? 0.03125f : vstate[t];
        __syncthreads();

        float* cur = vA;
        float* nxt = vB;

        for (int it = it0; it < it1; ++it) {
            float u = dgv * cur[t];
#pragma unroll
            for (int i = 0; i < RMAX; ++i) u -= w[i] * cur[src[i]];
            for (int p = tp0; p < p1; ++p) {
                const int2 e = pk_raw[p];
                u -= __int_as_float(e.x) * cur[e.y];
            }
            if ((it % NORM_EVERY) == NORM_EVERY - 1) {
                float sr = u * u;
#pragma unroll
                for (int o = 32; o > 0; o >>= 1) sr += __shfl_down(sr, o, 64);
                if ((t & 63) == 0) red[t >> 6] = sr;
                __syncthreads();
                if (t < 64) {
                    float xs = (t < 16) ? red[t] : 0.f;
#pragma unroll
                    for (int o = 8; o > 0; o >>= 1) xs += __shfl_down(xs, o, 64);
                    if (t == 0) red[16] = 1.0f / (sqrtf(xs) + 1e-12f);
                }
                __syncthreads();
                nxt[t] = u * red[16];
            } else {
                nxt[t] = u;
            }
            __syncthreads();
            float* tmp = cur; cur = nxt; nxt = tmp;
        }

        if (!finalize) {
            vstate[t] = cur[t];
            return;
        }
        // final matvec + Rayleigh quotient
        float u = dgv * cur[t];
#pragma unroll
        for (int i = 0; i < RMAX; ++i) u -= w[i] * cur[src[i]];
        for (int p = tp0; p < p1; ++p) {
            const int2 e = pk_raw[p];
            u -= __int_as_float(e.x) * cur[e.y];
        }
        float sr = cur[t] * u;
#pragma unroll
        for (int o = 32; o > 0; o >>= 1) sr += __shfl_down(sr, o, 64);
        if ((t & 63) == 0) red[t >> 6] = sr;
        __syncthreads();
        if (t == 0) {
            float lm = 0.f;
            for (int i = 0; i < 16; ++i) lm += red[i];
            scal[0] = lm;
            scal[1] = 2.0f / lm;
        }
        return;
    }

    // ---------------- prop path: y = deg_relu .* in - agg(in) ----------------
    const int b1   = blockIdx.x - 1;
    const int bid  = ((b1 & 7) << 10) + (b1 >> 3);     // XCD swizzle over 8192
    const int lane = threadIdx.x & 63;
    const int gnode = __builtin_amdgcn_readfirstlane(bid * 16 + (threadIdx.x >> 6));
    const int b = gnode >> 10, d = gnode & 1023;

    const int p0 = __builtin_amdgcn_readfirstlane(ptrg[d]);
    const int p1 = __builtin_amdgcn_readfirstlane(ptrg[d + 1]);
    const char* xb = (const char*)(in + (size_t)b * (NNODE * F_IN));

    float acc = 0.f;
    int p = p0;
    for (; p + 4 <= p1; p += 4) {
        const int2 e0 = pk2[p],     e1 = pk2[p + 1];
        const int2 e2 = pk2[p + 2], e3 = pk2[p + 3];
        const float v0 = ((const float*)(xb + (unsigned)e0.y))[lane];
        const float v1 = ((const float*)(xb + (unsigned)e1.y))[lane];
        const float v2 = ((const float*)(xb + (unsigned)e2.y))[lane];
        const float v3 = ((const float*)(xb + (unsigned)e3.y))[lane];
        acc += __int_as_float(e0.x) * v0;
        acc += __int_as_float(e1.x) * v1;
        acc += __int_as_float(e2.x) * v2;
        acc += __int_as_float(e3.x) * v3;
    }
    for (; p < p1; ++p) {
        const int2 e = pk2[p];
        acc += __int_as_float(e.x) * ((const float*)(xb + (unsigned)e.y))[lane];
    }

    const size_t gi = (size_t)gnode * F_IN + lane;
    const float xv = in[gi];
    const float o = dgl[d] * xv - acc;
    if (out32) out32[gi] = o;
    tcat[(size_t)gnode * 192 + slice * 64 + lane] = f2bf(o);
    if (writeX) tcat[(size_t)gnode * 192 + lane] = f2bf(xv);
}

// ---------------------------------------------------------------------------
// Kernel 3: bf16 MFMA fused cheb-GEMM + conv1d. Output bf16.
// ---------------------------------------------------------------------------
__global__ __launch_bounds__(256) void k_cheb_mfma(
    const unsigned short* __restrict__ tcat,
    const unsigned short* __restrict__ wcatT,
    const unsigned short* __restrict__ cvw,
    const float* __restrict__ chebB, const float* __restrict__ convB,
    unsigned short* __restrict__ cout)
{
    __shared__ __align__(16) char smem[49152];   // Bs (48K) / hS(32K)+cwS(16K)
    __shared__ float cb_s[HID];
    __shared__ float cvb_s[C1];

    const int t    = threadIdx.x;
    const int lane = t & 63;
    const int wid  = t >> 6;
    const int l15  = lane & 15;
    const int l4   = lane >> 4;
    const int rbase = blockIdx.x * 128;
    const int bb = rbase >> 10;
    const int n0 = rbase & 1023;

    if (t < HID) cb_s[t] = chebB[t];
    if (t < C1)  cvb_s[t] = convB[t];

    // stage W^T [n=128][k-slot 0..23] with slot XOR (n&7) swizzle
    for (int it = 0; it < 12; ++it) {
        const int gslot = it * 256 + t;          // 0..3071
        const int n = gslot / 24, q = gslot % 24;
        const bf16x8 v = *(const bf16x8*)(wcatT + n * 192 + q * 8);
        *(bf16x8*)(smem + n * 384 + ((q ^ (n & 7)) << 4)) = v;
    }
    __syncthreads();

    // ---- Phase A: 16x16x32 MFMA, A-frags straight from global ----
    const int rw = rbase + wid * 32;
    f32x4 acc[2][8];
#pragma unroll
    for (int m = 0; m < 2; ++m)
#pragma unroll
        for (int n = 0; n < 8; ++n) acc[m][n] = (f32x4)(0.f);

    const unsigned short* ta = tcat + (size_t)(rw + l15) * 192 + l4 * 8;
    bf16x8 a0 = *(const bf16x8*)(ta);
    bf16x8 a1 = *(const bf16x8*)(ta + 16 * 192);

#pragma unroll
    for (int ks = 0; ks < 6; ++ks) {
        bf16x8 na0, na1;
        if (ks < 5) {
            na0 = *(const bf16x8*)(ta + (ks + 1) * 32);
            na1 = *(const bf16x8*)(ta + 16 * 192 + (ks + 1) * 32);
        }
        const int kb = ks * 4 + l4;
#pragma unroll
        for (int nb = 0; nb < 8; ++nb) {
            const int n = nb * 16 + l15;
            const bf16x8 bv =
                *(const bf16x8*)(smem + n * 384 + ((kb ^ (n & 7)) << 4));
            acc[0][nb] = __builtin_amdgcn_mfma_f32_16x16x32_bf16(
                a0, bv, acc[0][nb], 0, 0, 0);
            acc[1][nb] = __builtin_amdgcn_mfma_f32_16x16x32_bf16(
                a1, bv, acc[1][nb], 0, 0, 0);
        }
        a0 = na0; a1 = na1;
    }
    __syncthreads();   // Bs dead

    // write h (+cheb bias) as bf16 into hS[node][c] (swizzled), smem+0..32K
#pragma unroll
    for (int mf = 0; mf < 2; ++mf)
#pragma unroll
        for (int nb = 0; nb < 8; ++nb) {
            const int c = nb * 16 + l15;
            const int slot = c >> 3;
            const float cb = cb_s[c];
#pragma unroll
            for (int reg = 0; reg < 4; ++reg) {
                const int node = wid * 32 + mf * 16 + l4 * 4 + reg;
                *(unsigned short*)(smem + node * 256 +
                                   ((slot ^ (node & 7)) << 4) + (c & 7) * 2) =
                    f2bf(acc[mf][nb][reg] + cb);
            }
        }
    // stage convW [c1][128] bf16 swizzled at smem+32768
    for (int it = 0; it < 4; ++it) {
        const int gslot = it * 256 + t;          // 0..1023
        const int c1i = gslot >> 4, q = gslot & 15;
        const bf16x8 v = *(const bf16x8*)(cvw + c1i * 128 + q * 8);
        *(bf16x8*)(smem + 32768 + c1i * 256 + ((q ^ (c1i & 7)) << 4)) = v;
    }
    __syncthreads();

    // ---- Phase B: c1 x node = convW @ h^T ----
    f32x4 acc2[8];
#pragma unroll
    for (int n = 0; n < 8; ++n) acc2[n] = (f32x4)(0.f);

#pragma unroll
    for (int ks = 0; ks < 4; ++ks) {
        const int kb = ks * 4 + l4;
        const int c1a = wid * 16 + l15;
        const bf16x8 av = *(const bf16x8*)(smem + 32768 + c1a * 256 +
                                           ((kb ^ (c1a & 7)) << 4));
#pragma unroll
        for (int nb = 0; nb < 8; ++nb) {
            const int node = nb * 16 + l15;
            const bf16x8 bv =
                *(const bf16x8*)(smem + node * 256 + ((kb ^ (node & 7)) << 4));
            acc2[nb] = __builtin_amdgcn_mfma_f32_16x16x32_bf16(
                av, bv, acc2[nb], 0, 0, 0);
        }
    }

#pragma unroll
    for (int nb = 0; nb < 8; ++nb) {
        const int ng = n0 + nb * 16 + l15;
#pragma unroll
        for (int reg = 0; reg < 4; ++reg) {
            const int c1i = wid * 16 + l4 * 4 + reg;
            cout[(size_t)bb * (C1 * NNODE) + (size_t)c1i * NNODE + ng] =
                f2bf(fmaxf(acc2[nb][reg] + cvb_s[c1i], 0.f));
        }
    }
}

// ---------------------------------------------------------------------------
// Kernel 4: fc1 partials (K-split over 256-col chunks), bf16 input.
// ---------------------------------------------------------------------------
__global__ __launch_bounds__(256) void k_fc1(
    const unsigned short* __restrict__ cf, const float* __restrict__ W,
    float* __restrict__ part)
{
    __shared__ float Wt[256 * 33];
    const int t = threadIdx.x;
    const int g = blockIdx.x;
    const int k0 = g * 256;

    for (int i = t; i < 8192; i += 256) {
        const int j = i >> 8, k = i & 255;
        Wt[k * 33 + j] = W[(size_t)j * (C1 * NNODE) + k0 + k];
    }
    __syncthreads();

    const int j = t & 31, bg = t >> 5;
    float acc[16];
#pragma unroll
    for (int i = 0; i < 16; ++i) acc[i] = 0.f;

    const unsigned short* cb = cf + (size_t)(bg * 16) * (C1 * NNODE) + k0;
    for (int k4 = 0; k4 < 64; ++k4) {
        const int kb = k4 * 4;
        const float w0 = Wt[(kb + 0) * 33 + j];
        const float w1 = Wt[(kb + 1) * 33 + j];
        const float w2 = Wt[(kb + 2) * 33 + j];
        const float w3 = Wt[(kb + 3) * 33 + j];
#pragma unroll
        for (int i = 0; i < 16; ++i) {
            const u16x4 cv = *(const u16x4*)&cb[(size_t)i * (C1 * NNODE) + kb];
            acc[i] += bf2f(cv[0]) * w0 + bf2f(cv[1]) * w1 +
                      bf2f(cv[2]) * w2 + bf2f(cv[3]) * w3;
        }
    }
#pragma unroll
    for (int i = 0; i < 16; ++i)
        part[(size_t)g * 4096 + (size_t)(bg * 16 + i) * 32 + j] = acc[i];
}

__global__ __launch_bounds__(256) void k_red(
    const float* __restrict__ part, float* __restrict__ z)
{
    const int o = blockIdx.x * 256 + threadIdx.x;
    float s = 0.f;
    for (int g = 0; g < 256; ++g) s += part[(size_t)g * 4096 + o];
    z[o] = s;
}

__global__ __launch_bounds__(128) void k_head(
    const float* __restrict__ z, const float* __restrict__ b1,
    const float* __restrict__ W2, const float* __restrict__ b2,
    float* __restrict__ outp)
{
    const int b = threadIdx.x;
    float a[32];
#pragma unroll
    for (int j = 0; j < 32; ++j) a[j] = z[b * 32 + j] + b1[j];
    float l[4];
#pragma unroll
    for (int c = 0; c < 4; ++c) {
        float s = b2[c];
#pragma unroll
        for (int j = 0; j < 32; ++j) s += W2[c * 32 + j] * a[j];
        l[c] = s;
    }
    const float m = fmaxf(fmaxf(l[0], l[1]), fmaxf(l[2], l[3]));
    const float e0 = expf(l[0] - m), e1 = expf(l[1] - m);
    const float e2 = expf(l[2] - m), e3 = expf(l[3] - m);
    const float inv = 1.f / (e0 + e1 + e2 + e3);
    outp[b * 4 + 0] = e0 * inv;
    outp[b * 4 + 1] = e1 * inv;
    outp[b * 4 + 2] = e2 * inv;
    outp[b * 4 + 3] = e3 * inv;
}

// ---------------------------------------------------------------------------
extern "C" void kernel_launch(void* const* d_in, const int* in_sizes, int n_in,
                              void* d_out, int out_size, void* d_ws, size_t ws_size,
                              hipStream_t stream)
{
    const float* x     = (const float*)d_in[0];
    const int*   ei    = (const int*)d_in[1];
    const float* ew    = (const float*)d_in[2];
    const float* chebW = (const float*)d_in[3];
    const float* chebB = (const float*)d_in[4];
    const float* convW = (const float*)d_in[5];
    const float* convB = (const float*)d_in[6];
    const float* fc1W  = (const float*)d_in[7];
    const float* fc1B  = (const float*)d_in[8];
    const float* fc2W  = (const float*)d_in[9];
    const float* fc2B  = (const float*)d_in[10];
    float* out = (float*)d_out;

    char* ws = (char*)d_ws;
    float* scal   = (float*)(ws + 0);
    float* vstate = (float*)(ws + 4096);           // 4KB lmax state handoff
    char*  partb = ws + 8192;                      // 4MB multi-use region
    int*   ptr  = (int*)(partb + 8192);
    float* dgr  = (float*)(partb + 16384);
    float* dgl  = (float*)(partb + 20480);
    int2*  pk   = (int2*)(partb + 24576);          // 128KB (raw w, src)
    unsigned short* wcatT = (unsigned short*)(partb + 262144);  // 48KB
    unsigned short* cvwB  = (unsigned short*)(partb + 327680);  // 16KB
    int2*  pk2  = (int2*)(partb + 458752);         // 128KB (relu w, src*256)
    float* part = (float*)partb;                   // fc1 partials (after cheb)
    float* z    = (float*)(ws + 8192 + 4194304);
    float* y1   = (float*)(ws + 8192 + 4194304 + 65536);        // 32MB (Lx)
    unsigned short* tcat = (unsigned short*)((char*)y1 + 33554432); // 48MB
    unsigned short* cbuf = (unsigned short*)((char*)tcat + 50331648); // 16MB

    k_csr <<<dim3(1), dim3(1024), 0, stream>>>(ei, ew, ptr, dgr, dgl, pk, pk2);

    // fused: {lmax iters 0-25 || y1 = Lx}, then {lmax 25-50+Rayleigh || y2=L y1}
    k_fused<<<dim3(BN / 16 + 1), dim3(1024), 0, stream>>>(
        x, pk, pk2, ptr, dgr, dgl, vstate, scal,
        y1, tcat, 1, 1, 0, 25, 0);
    k_fused<<<dim3(BN / 16 + 1), dim3(1024), 0, stream>>>(
        y1, pk, pk2, ptr, dgr, dgl, vstate, scal,
        (float*)nullptr, tcat, 2, 0, 25, 50, 1);

    k_cvtw<<<dim3(128), dim3(256), 0, stream>>>(chebW, convW, scal, wcatT, cvwB);

    k_cheb_mfma<<<dim3(BN / 128), dim3(256), 0, stream>>>(
        tcat, wcatT, cvwB, chebB, convB, cbuf);

    k_fc1<<<dim3(256), dim3(256), 0, stream>>>(cbuf, fc1W, part);
    k_red<<<dim3(16), dim3(256), 0, stream>>>(part, z);
    k_head<<<dim3(1), dim3(128), 0, stream>>>(z, fc1B, fc2W, fc2B, out);
}